// Round 1
// baseline (1545.355 us; speedup 1.0000x reference)
//
#include <hip/hip_runtime.h>
#include <math.h>

#define B_    2
#define S_    1024
#define HID_  2048
#define NH_   16
#define NKV_  4
#define HD_   128
#define GROUPS (NH_ / NKV_)
#define SCALE_ 0.08838834764831845f   // 1/sqrt(128)

// ---------------------------------------------------------------------------
// Tiled f32 GEMM: C[m,n] = sum_k A[m,k] * W[n,k]   (A: MxK row-major, W: NxK)
// mode==1: write C into (b, h, s, d) layout with h = n>>7, d = n&127,
//          b = m>>10, s = m&1023  (S_=1024, HD_=128)
// mode==0: plain row-major MxN write.
// ---------------------------------------------------------------------------
#define GT  64
#define GK  16
#define GKP 20

__global__ __launch_bounds__(256) void gemm_xt(
    const float* __restrict__ A, const float* __restrict__ W,
    float* __restrict__ C, int K, int headsOut, int mode, int N)
{
    __shared__ float As[GT][GKP];
    __shared__ float Ws[GT][GKP];

    const int tid = threadIdx.x;
    const int tx = tid & 15, ty = tid >> 4;
    const int bm = blockIdx.y * GT, bn = blockIdx.x * GT;

    float acc[4][4] = {};

    const int lr = tid >> 2;          // 0..63
    const int lc = (tid & 3) * 4;     // 0,4,8,12
    const float* Ap = A + (size_t)(bm + lr) * K + lc;
    const float* Wp = W + (size_t)(bn + lr) * K + lc;

    for (int k0 = 0; k0 < K; k0 += GK) {
        float4 av = *(const float4*)(Ap + k0);
        float4 wv = *(const float4*)(Wp + k0);
        __syncthreads();
        *(float4*)&As[lr][lc] = av;
        *(float4*)&Ws[lr][lc] = wv;
        __syncthreads();
#pragma unroll
        for (int kk = 0; kk < GK; kk += 4) {
            float4 a[4], w[4];
#pragma unroll
            for (int i = 0; i < 4; i++) a[i] = *(float4*)&As[ty + 16 * i][kk];
#pragma unroll
            for (int j = 0; j < 4; j++) w[j] = *(float4*)&Ws[tx + 16 * j][kk];
#pragma unroll
            for (int i = 0; i < 4; i++)
#pragma unroll
                for (int j = 0; j < 4; j++)
                    acc[i][j] += a[i].x * w[j].x + a[i].y * w[j].y +
                                 a[i].z * w[j].z + a[i].w * w[j].w;
        }
    }

#pragma unroll
    for (int i = 0; i < 4; i++) {
        int m = bm + ty + 16 * i;
#pragma unroll
        for (int j = 0; j < 4; j++) {
            int n = bn + tx + 16 * j;
            if (mode == 1) {
                int h = n >> 7, d = n & 127;
                int b = m >> 10, s = m & 1023;
                C[(((size_t)(b * headsOut + h)) * S_ + s) * HD_ + d] = acc[i][j];
            } else {
                C[(size_t)m * N + n] = acc[i][j];
            }
        }
    }
}

// ---------------------------------------------------------------------------
// Fused RoPE + RMSNorm, in-place on (rows, 128) where row = (b*H+h)*S + s.
// Lane t (0..63) owns the rotation pair (t, t+64). 4 rows per 256-thread block.
// ---------------------------------------------------------------------------
__global__ __launch_bounds__(256) void rope_rms(
    float* __restrict__ x, const float* __restrict__ w, int nrows)
{
    int row = blockIdx.x * 4 + (threadIdx.x >> 6);
    int lane = threadIdx.x & 63;
    if (row >= nrows) return;
    int s = row & (S_ - 1);

    float* p = x + (size_t)row * HD_;
    float x1 = p[lane], x2 = p[lane + 64];

    // inv_freq = 10000^(-lane/64) = 2^(-lane * log2(10000)/64)
    float invf = exp2f(-(float)lane * 0.2076205059304601f);
    float ang = (float)s * invf;
    float c, sn;
    sincosf(ang, &sn, &c);

    float y1 = x1 * c - x2 * sn;
    float y2 = x1 * sn + x2 * c;

    float ss = y1 * y1 + y2 * y2;
#pragma unroll
    for (int off = 32; off > 0; off >>= 1) ss += __shfl_xor(ss, off);

    float scl = rsqrtf(ss * (1.0f / 128.0f) + 1e-6f);
    p[lane]      = y1 * scl * w[lane];
    p[lane + 64] = y2 * scl * w[lane + 64];
}

// ---------------------------------------------------------------------------
// Stick-breaking attention, flash-style, reverse key-block sweep.
// Grid: (S/BQ, NH, B). Block: 256 threads. f32 throughout.
// att[i,j] = sigmoid(l_ij) * exp( sum_{j<j'<i} log_sigmoid(-l_ij') ), j<i
// Processed key blocks in descending j; accs[q] holds the suffix sum over
// already-processed (higher-j) blocks; within-block exclusive suffix scan.
// Output written to AO in (b, s, h, d) layout for the Wo GEMM.
// ---------------------------------------------------------------------------
#define BQ 32
#define BK 32
#define HDP (HD_ + 4)

__device__ __forceinline__ float logsig(float x) {
    // stable log(sigmoid(x)) = min(x,0) - log1p(exp(-|x|))
    return fminf(x, 0.0f) - log1pf(expf(-fabsf(x)));
}

__global__ __launch_bounds__(256) void stick_attn(
    const float* __restrict__ Q, const float* __restrict__ K,
    const float* __restrict__ V, float* __restrict__ AO)
{
    __shared__ float Qs[BQ][HDP];
    __shared__ float Ks[BK][HDP];
    __shared__ float Vs[BK][HDP];
    __shared__ float Ls[BQ][BK + 1];
    __shared__ float LPs[BQ][BK + 1];
    __shared__ float LOs[BQ][BK + 1];
    __shared__ float accs[BQ];

    const int qb = blockIdx.x, h = blockIdx.y, b = blockIdx.z;
    const int kvh = h / GROUPS;
    const int tid = threadIdx.x;
    const int qi0 = qb * BQ;

    const float* Qbase = Q + ((size_t)(b * NH_ + h) * S_ + qi0) * HD_;
    const float* Kbase = K + ((size_t)(b * NKV_ + kvh) * S_) * HD_;
    const float* Vbase = V + ((size_t)(b * NKV_ + kvh) * S_) * HD_;

    // Q tile: 32 rows x 128 = 1024 float4
    for (int i = tid; i < BQ * HD_ / 4; i += 256) {
        int r = i >> 5, c = (i & 31) * 4;
        *(float4*)&Qs[r][c] = *(const float4*)(Qbase + r * HD_ + c);
    }
    if (tid < BQ) accs[tid] = 0.0f;

    float o[16] = {};
    const int oq = tid >> 3;              // 0..31 query row
    const int odb = (tid & 7) * 4;        // d chunks: odb + 32*c, c=0..3

    const int lq = tid & 31;              // logits: query row
    const int lj0 = (tid >> 5) * 4;       // logits: 4 keys starting here

    for (int kb = qb; kb >= 0; --kb) {
        __syncthreads();
        for (int i = tid; i < BK * HD_ / 4; i += 256) {
            int r = i >> 5, c = (i & 31) * 4;
            *(float4*)&Ks[r][c] = *(const float4*)(Kbase + (kb * BK + r) * HD_ + c);
            *(float4*)&Vs[r][c] = *(const float4*)(Vbase + (kb * BK + r) * HD_ + c);
        }
        __syncthreads();

        // logits: each thread does 4 dots of length 128 from LDS
        {
            float d0 = 0, d1 = 0, d2 = 0, d3 = 0;
#pragma unroll 4
            for (int kk = 0; kk < HD_; kk += 4) {
                float4 qv = *(float4*)&Qs[lq][kk];
                float4 k0 = *(float4*)&Ks[lj0 + 0][kk];
                float4 k1 = *(float4*)&Ks[lj0 + 1][kk];
                float4 k2 = *(float4*)&Ks[lj0 + 2][kk];
                float4 k3 = *(float4*)&Ks[lj0 + 3][kk];
                d0 += qv.x * k0.x + qv.y * k0.y + qv.z * k0.z + qv.w * k0.w;
                d1 += qv.x * k1.x + qv.y * k1.y + qv.z * k1.z + qv.w * k1.w;
                d2 += qv.x * k2.x + qv.y * k2.y + qv.z * k2.z + qv.w * k2.w;
                d3 += qv.x * k3.x + qv.y * k3.y + qv.z * k3.z + qv.w * k3.w;
            }
            Ls[lq][lj0 + 0] = d0 * SCALE_;
            Ls[lq][lj0 + 1] = d1 * SCALE_;
            Ls[lq][lj0 + 2] = d2 * SCALE_;
            Ls[lq][lj0 + 3] = d3 * SCALE_;
        }
        __syncthreads();

        // log_p and masked log_om
#pragma unroll
        for (int e = 0; e < 4; e++) {
            int idx = tid + e * 256;
            int q = idx >> 5, j = idx & 31;
            float L = Ls[q][j];
            bool valid = (kb * BK + j) < (qi0 + q);
            LPs[q][j] = logsig(L);
            LOs[q][j] = valid ? logsig(-L) : 0.0f;
        }
        __syncthreads();

        // per-row exclusive suffix scan of LOs (32 threads, one per query)
        float blocksum = 0.0f;
        if (tid < BQ) {
            float run = 0.0f;
#pragma unroll
            for (int j = BK - 1; j >= 0; --j) {
                float t = LOs[tid][j];
                LOs[tid][j] = run;
                run += t;
            }
            blocksum = run;
        }
        __syncthreads();

        // att = exp(log_p + within-block suffix + suffix of later blocks)
#pragma unroll
        for (int e = 0; e < 4; e++) {
            int idx = tid + e * 256;
            int q = idx >> 5, j = idx & 31;
            bool valid = (kb * BK + j) < (qi0 + q);
            float a = valid ? expf(LPs[q][j] + LOs[q][j] + accs[q]) : 0.0f;
            LPs[q][j] = a;   // LPs now holds att
        }
        __syncthreads();
        if (tid < BQ) accs[tid] += blocksum;

        // o += att @ V
#pragma unroll
        for (int j = 0; j < BK; ++j) {
            float a = LPs[oq][j];
#pragma unroll
            for (int c = 0; c < 4; c++) {
                float4 vv = *(float4*)&Vs[j][odb + 32 * c];
                o[c * 4 + 0] += a * vv.x;
                o[c * 4 + 1] += a * vv.y;
                o[c * 4 + 2] += a * vv.z;
                o[c * 4 + 3] += a * vv.w;
            }
        }
    }

    // write to (b, s, h, d)
    float* dst = AO + ((size_t)(b * S_ + qi0 + oq) * NH_ + h) * HD_;
#pragma unroll
    for (int c = 0; c < 4; c++) {
        float4 vv = make_float4(o[c * 4 + 0], o[c * 4 + 1],
                                o[c * 4 + 2], o[c * 4 + 3]);
        *(float4*)(dst + odb + 32 * c) = vv;
    }
}

// ---------------------------------------------------------------------------
extern "C" void kernel_launch(void* const* d_in, const int* in_sizes, int n_in,
                              void* d_out, int out_size, void* d_ws, size_t ws_size,
                              hipStream_t stream)
{
    const float* hs = (const float*)d_in[0];
    const float* Wq = (const float*)d_in[1];
    const float* Wk = (const float*)d_in[2];
    const float* Wv = (const float*)d_in[3];
    const float* Wo = (const float*)d_in[4];
    const float* qw = (const float*)d_in[5];
    const float* kw = (const float*)d_in[6];
    float* out = (float*)d_out;

    float* ws   = (float*)d_ws;
    float* q_ws = ws;                                        // B*NH*S*HD  = 4194304 f
    float* k_ws = q_ws + (size_t)B_ * NH_ * S_ * HD_;        // B*NKV*S*HD = 1048576 f
    float* v_ws = k_ws + (size_t)B_ * NKV_ * S_ * HD_;       // B*NKV*S*HD = 1048576 f
    float* ao_ws = v_ws + (size_t)B_ * NKV_ * S_ * HD_;      // B*S*HID    = 4194304 f

    dim3 blk(256);
    const int M = B_ * S_;   // 2048

    // Q/K/V projections -> (b, head, s, d)
    gemm_xt<<<dim3(HID_ / GT, M / GT), blk, 0, stream>>>(hs, Wq, q_ws, HID_, NH_, 1, HID_);
    gemm_xt<<<dim3((NKV_ * HD_) / GT, M / GT), blk, 0, stream>>>(hs, Wk, k_ws, HID_, NKV_, 1, NKV_ * HD_);
    gemm_xt<<<dim3((NKV_ * HD_) / GT, M / GT), blk, 0, stream>>>(hs, Wv, v_ws, HID_, NKV_, 1, NKV_ * HD_);

    // RoPE + RMSNorm on Q and K
    rope_rms<<<dim3(B_ * NH_ * S_ / 4), blk, 0, stream>>>(q_ws, qw, B_ * NH_ * S_);
    rope_rms<<<dim3(B_ * NKV_ * S_ / 4), blk, 0, stream>>>(k_ws, kw, B_ * NKV_ * S_);

    // stick-breaking attention -> (b, s, h, d)
    stick_attn<<<dim3(S_ / BQ, NH_, B_), blk, 0, stream>>>(q_ws, k_ws, v_ws, ao_ws);

    // output projection
    gemm_xt<<<dim3(HID_ / GT, M / GT), blk, 0, stream>>>(ao_ws, Wo, out, HID_, 0, 0, HID_);
}

// Round 2
// 839.388 us; speedup vs baseline: 1.8410x; 1.8410x over previous
//
#include <hip/hip_runtime.h>
#include <hip/hip_bf16.h>
#include <math.h>

#define B_    2
#define S_    1024
#define HID_  2048
#define NH_   16
#define NKV_  4
#define HD_   128
#define GROUPS (NH_ / NKV_)
#define SCALE_ 0.08838834764831845f   // 1/sqrt(128)

typedef __bf16 bf16x8 __attribute__((ext_vector_type(8)));
typedef float  f32x4  __attribute__((ext_vector_type(4)));

// ---------------------------------------------------------------------------
// f32 -> bf16 cast (RNE), 4 elems/thread
// ---------------------------------------------------------------------------
__global__ __launch_bounds__(256) void cast_bf16(
    const float4* __restrict__ x, ushort4* __restrict__ y, int n4)
{
    int i = blockIdx.x * 256 + threadIdx.x;
    if (i >= n4) return;
    float4 v = x[i];
    __hip_bfloat16 a = __float2bfloat16(v.x), b = __float2bfloat16(v.y),
                   c = __float2bfloat16(v.z), d = __float2bfloat16(v.w);
    ushort4 o;
    o.x = *(unsigned short*)&a; o.y = *(unsigned short*)&b;
    o.z = *(unsigned short*)&c; o.w = *(unsigned short*)&d;
    y[i] = o;
}

// ---------------------------------------------------------------------------
// bf16 MFMA GEMM: C[m,n] = sum_k A[m,k] * W[n,k], f32 accumulate/output.
// 128x128 tile, BK=32, 256 threads = 4 waves, each wave 64x64 via 4x4
// grid of v_mfma_f32_16x16x32_bf16.
// mode 0: C[m*N+n]
// mode 1: scatter to (b, h, s, d), h=n>>7, d=n&127, b=m>>10, s=m&1023
// mode 2: fused K|V: bn<512 -> (W,C) with heads, else (W2,C2), n-=512
// ---------------------------------------------------------------------------
__global__ __launch_bounds__(256) void gemm_mfma(
    const __hip_bfloat16* __restrict__ A,
    const __hip_bfloat16* __restrict__ W,
    const __hip_bfloat16* __restrict__ W2,
    float* __restrict__ C, float* __restrict__ C2,
    int K, int N, int mode, int heads)
{
    __shared__ __align__(16) __hip_bfloat16 As[128][32];
    __shared__ __align__(16) __hip_bfloat16 Ws[128][32];

    const int tid  = threadIdx.x;
    const int lane = tid & 63, wave = tid >> 6;
    const int wr = (wave >> 1) * 64, wc = (wave & 1) * 64;
    const int bm = blockIdx.y * 128;
    int bn = blockIdx.x * 128;

    const __hip_bfloat16* Wp = W;
    float* Cp = C;
    if (mode == 2 && bn >= 512) { Wp = W2; Cp = C2; bn -= 512; }

    // staging: thread -> 2 rows of A and W, 16B (8 bf16) each
    const int r0 = tid >> 2, c0 = (tid & 3) * 8;
    const __hip_bfloat16* Ag0 = A  + (size_t)(bm + r0)      * K + c0;
    const __hip_bfloat16* Ag1 = A  + (size_t)(bm + r0 + 64) * K + c0;
    const __hip_bfloat16* Wg0 = Wp + (size_t)(bn + r0)      * K + c0;
    const __hip_bfloat16* Wg1 = Wp + (size_t)(bn + r0 + 64) * K + c0;

    f32x4 acc[4][4];
    const f32x4 fz = {0.f, 0.f, 0.f, 0.f};
#pragma unroll
    for (int i = 0; i < 4; i++)
#pragma unroll
        for (int j = 0; j < 4; j++) acc[i][j] = fz;

    const int ml = lane & 15, kg = lane >> 4;

    for (int k0 = 0; k0 < K; k0 += 32) {
        float4 av0 = *(const float4*)(Ag0 + k0);
        float4 av1 = *(const float4*)(Ag1 + k0);
        float4 wv0 = *(const float4*)(Wg0 + k0);
        float4 wv1 = *(const float4*)(Wg1 + k0);
        __syncthreads();
        *(float4*)&As[r0][c0]      = av0;
        *(float4*)&As[r0 + 64][c0] = av1;
        *(float4*)&Ws[r0][c0]      = wv0;
        *(float4*)&Ws[r0 + 64][c0] = wv1;
        __syncthreads();

        bf16x8 a[4], b[4];
#pragma unroll
        for (int mi = 0; mi < 4; mi++)
            a[mi] = *(const bf16x8*)&As[wr + mi * 16 + ml][kg * 8];
#pragma unroll
        for (int ni = 0; ni < 4; ni++)
            b[ni] = *(const bf16x8*)&Ws[wc + ni * 16 + ml][kg * 8];
#pragma unroll
        for (int mi = 0; mi < 4; mi++)
#pragma unroll
            for (int ni = 0; ni < 4; ni++)
                acc[mi][ni] = __builtin_amdgcn_mfma_f32_16x16x32_bf16(
                    a[mi], b[ni], acc[mi][ni], 0, 0, 0);
    }

    // epilogue: C/D layout col=lane&15, row=(lane>>4)*4+reg
#pragma unroll
    for (int mi = 0; mi < 4; mi++) {
#pragma unroll
        for (int ni = 0; ni < 4; ni++) {
#pragma unroll
            for (int r = 0; r < 4; r++) {
                int m = bm + wr + mi * 16 + kg * 4 + r;
                int n = bn + wc + ni * 16 + ml;
                float v = acc[mi][ni][r];
                if (mode == 0) {
                    Cp[(size_t)m * N + n] = v;
                } else {
                    int h = n >> 7, d = n & 127;
                    int b_ = m >> 10, s = m & 1023;
                    Cp[(((size_t)(b_ * heads + h)) * S_ + s) * HD_ + d] = v;
                }
            }
        }
    }
}

// ---------------------------------------------------------------------------
// Fused RoPE + RMSNorm, in-place on (rows, 128) where row = (b*H+h)*S + s.
// ---------------------------------------------------------------------------
__global__ __launch_bounds__(256) void rope_rms(
    float* __restrict__ x, const float* __restrict__ w, int nrows)
{
    int row = blockIdx.x * 4 + (threadIdx.x >> 6);
    int lane = threadIdx.x & 63;
    if (row >= nrows) return;
    int s = row & (S_ - 1);

    float* p = x + (size_t)row * HD_;
    float x1 = p[lane], x2 = p[lane + 64];

    float invf = exp2f(-(float)lane * 0.2076205059304601f);
    float ang = (float)s * invf;
    float c, sn;
    sincosf(ang, &sn, &c);

    float y1 = x1 * c - x2 * sn;
    float y2 = x1 * sn + x2 * c;

    float ss = y1 * y1 + y2 * y2;
#pragma unroll
    for (int off = 32; off > 0; off >>= 1) ss += __shfl_xor(ss, off);

    float scl = rsqrtf(ss * (1.0f / 128.0f) + 1e-6f);
    p[lane]      = y1 * scl * w[lane];
    p[lane + 64] = y2 * scl * w[lane + 64];
}

// ---------------------------------------------------------------------------
// Stick-breaking attention, reverse key-block sweep. Heavy blocks first
// (qb = gridDim.x-1-blockIdx.x) for load balance.
// ---------------------------------------------------------------------------
#define BQ 32
#define BK 32
#define HDP (HD_ + 4)

__device__ __forceinline__ float logsig(float x) {
    return fminf(x, 0.0f) - log1pf(expf(-fabsf(x)));
}

__global__ __launch_bounds__(256) void stick_attn(
    const float* __restrict__ Q, const float* __restrict__ K,
    const float* __restrict__ V, float* __restrict__ AO)
{
    __shared__ float Qs[BQ][HDP];
    __shared__ float Ks[BK][HDP];
    __shared__ float Vs[BK][HDP];
    __shared__ float Ls[BQ][BK + 1];
    __shared__ float LPs[BQ][BK + 1];
    __shared__ float LOs[BQ][BK + 1];
    __shared__ float accs[BQ];

    const int qb = gridDim.x - 1 - blockIdx.x;   // heavy blocks dispatch first
    const int h = blockIdx.y, b = blockIdx.z;
    const int kvh = h / GROUPS;
    const int tid = threadIdx.x;
    const int qi0 = qb * BQ;

    const float* Qbase = Q + ((size_t)(b * NH_ + h) * S_ + qi0) * HD_;
    const float* Kbase = K + ((size_t)(b * NKV_ + kvh) * S_) * HD_;
    const float* Vbase = V + ((size_t)(b * NKV_ + kvh) * S_) * HD_;

    for (int i = tid; i < BQ * HD_ / 4; i += 256) {
        int r = i >> 5, c = (i & 31) * 4;
        *(float4*)&Qs[r][c] = *(const float4*)(Qbase + r * HD_ + c);
    }
    if (tid < BQ) accs[tid] = 0.0f;

    float o[16] = {};
    const int oq = tid >> 3;
    const int odb = (tid & 7) * 4;

    const int lq = tid & 31;
    const int lj0 = (tid >> 5) * 4;

    for (int kb = qb; kb >= 0; --kb) {
        __syncthreads();
        for (int i = tid; i < BK * HD_ / 4; i += 256) {
            int r = i >> 5, c = (i & 31) * 4;
            *(float4*)&Ks[r][c] = *(const float4*)(Kbase + (kb * BK + r) * HD_ + c);
            *(float4*)&Vs[r][c] = *(const float4*)(Vbase + (kb * BK + r) * HD_ + c);
        }
        __syncthreads();

        {
            float d0 = 0, d1 = 0, d2 = 0, d3 = 0;
#pragma unroll 4
            for (int kk = 0; kk < HD_; kk += 4) {
                float4 qv = *(float4*)&Qs[lq][kk];
                float4 k0 = *(float4*)&Ks[lj0 + 0][kk];
                float4 k1 = *(float4*)&Ks[lj0 + 1][kk];
                float4 k2 = *(float4*)&Ks[lj0 + 2][kk];
                float4 k3 = *(float4*)&Ks[lj0 + 3][kk];
                d0 += qv.x * k0.x + qv.y * k0.y + qv.z * k0.z + qv.w * k0.w;
                d1 += qv.x * k1.x + qv.y * k1.y + qv.z * k1.z + qv.w * k1.w;
                d2 += qv.x * k2.x + qv.y * k2.y + qv.z * k2.z + qv.w * k2.w;
                d3 += qv.x * k3.x + qv.y * k3.y + qv.z * k3.z + qv.w * k3.w;
            }
            Ls[lq][lj0 + 0] = d0 * SCALE_;
            Ls[lq][lj0 + 1] = d1 * SCALE_;
            Ls[lq][lj0 + 2] = d2 * SCALE_;
            Ls[lq][lj0 + 3] = d3 * SCALE_;
        }
        __syncthreads();

#pragma unroll
        for (int e = 0; e < 4; e++) {
            int idx = tid + e * 256;
            int q = idx >> 5, j = idx & 31;
            float L = Ls[q][j];
            bool valid = (kb * BK + j) < (qi0 + q);
            LPs[q][j] = logsig(L);
            LOs[q][j] = valid ? logsig(-L) : 0.0f;
        }
        __syncthreads();

        float blocksum = 0.0f;
        if (tid < BQ) {
            float run = 0.0f;
#pragma unroll
            for (int j = BK - 1; j >= 0; --j) {
                float t = LOs[tid][j];
                LOs[tid][j] = run;
                run += t;
            }
            blocksum = run;
        }
        __syncthreads();

#pragma unroll
        for (int e = 0; e < 4; e++) {
            int idx = tid + e * 256;
            int q = idx >> 5, j = idx & 31;
            bool valid = (kb * BK + j) < (qi0 + q);
            float a = valid ? expf(LPs[q][j] + LOs[q][j] + accs[q]) : 0.0f;
            LPs[q][j] = a;
        }
        __syncthreads();
        if (tid < BQ) accs[tid] += blocksum;

#pragma unroll
        for (int j = 0; j < BK; ++j) {
            float a = LPs[oq][j];
#pragma unroll
            for (int c = 0; c < 4; c++) {
                float4 vv = *(float4*)&Vs[j][odb + 32 * c];
                o[c * 4 + 0] += a * vv.x;
                o[c * 4 + 1] += a * vv.y;
                o[c * 4 + 2] += a * vv.z;
                o[c * 4 + 3] += a * vv.w;
            }
        }
    }

    float* dst = AO + ((size_t)(b * S_ + qi0 + oq) * NH_ + h) * HD_;
#pragma unroll
    for (int c = 0; c < 4; c++) {
        float4 vv = make_float4(o[c * 4 + 0], o[c * 4 + 1],
                                o[c * 4 + 2], o[c * 4 + 3]);
        *(float4*)(dst + odb + 32 * c) = vv;
    }
}

// ---------------------------------------------------------------------------
extern "C" void kernel_launch(void* const* d_in, const int* in_sizes, int n_in,
                              void* d_out, int out_size, void* d_ws, size_t ws_size,
                              hipStream_t stream)
{
    const float* hs = (const float*)d_in[0];
    const float* Wq = (const float*)d_in[1];
    const float* Wk = (const float*)d_in[2];
    const float* Wv = (const float*)d_in[3];
    const float* Wo = (const float*)d_in[4];
    const float* qw = (const float*)d_in[5];
    const float* kw = (const float*)d_in[6];
    float* out = (float*)d_out;

    // f32 workspace
    float* ws    = (float*)d_ws;
    float* q_ws  = ws;                     // 4,194,304 f
    float* k_ws  = q_ws + 4194304;         // 1,048,576 f
    float* v_ws  = k_ws + 1048576;         // 1,048,576 f
    float* ao_ws = v_ws + 1048576;         // 4,194,304 f
    // bf16 workspace (after f32 region)
    __hip_bfloat16* hsb = (__hip_bfloat16*)(ao_ws + 4194304); // 4,194,304
    __hip_bfloat16* Wqb = hsb + 4194304;   // 4,194,304
    __hip_bfloat16* Wkb = Wqb + 4194304;   // 1,048,576
    __hip_bfloat16* Wvb = Wkb + 1048576;   // 1,048,576
    // aliases (sequential stream ordering makes this safe)
    __hip_bfloat16* aob = hsb;
    __hip_bfloat16* Wob = Wqb;

    dim3 blk(256);

    // casts: hs, Wq (1M float4 each), Wk, Wv (256K float4 each)
    cast_bf16<<<4096, blk, 0, stream>>>((const float4*)hs, (ushort4*)hsb, 1048576);
    cast_bf16<<<4096, blk, 0, stream>>>((const float4*)Wq, (ushort4*)Wqb, 1048576);
    cast_bf16<<<1024, blk, 0, stream>>>((const float4*)Wk, (ushort4*)Wkb, 262144);
    cast_bf16<<<1024, blk, 0, stream>>>((const float4*)Wv, (ushort4*)Wvb, 262144);

    // Q projection -> (b,h,s,d); fused K|V projection -> (b,kvh,s,d)
    gemm_mfma<<<dim3(16, 16), blk, 0, stream>>>(hsb, Wqb, nullptr, q_ws, nullptr,
                                                HID_, 0, 1, NH_);
    gemm_mfma<<<dim3(8, 16), blk, 0, stream>>>(hsb, Wkb, Wvb, k_ws, v_ws,
                                               HID_, 0, 2, NKV_);

    // RoPE + RMSNorm
    rope_rms<<<dim3(B_ * NH_ * S_ / 4), blk, 0, stream>>>(q_ws, qw, B_ * NH_ * S_);
    rope_rms<<<dim3(B_ * NKV_ * S_ / 4), blk, 0, stream>>>(k_ws, kw, B_ * NKV_ * S_);

    // stick-breaking attention -> (b,s,h,d)
    stick_attn<<<dim3(S_ / BQ, NH_, B_), blk, 0, stream>>>(q_ws, k_ws, v_ws, ao_ws);

    // cast attention output + Wo, then output projection
    cast_bf16<<<4096, blk, 0, stream>>>((const float4*)ao_ws, (ushort4*)aob, 1048576);
    cast_bf16<<<4096, blk, 0, stream>>>((const float4*)Wo, (ushort4*)Wob, 1048576);
    gemm_mfma<<<dim3(16, 16), blk, 0, stream>>>(aob, Wob, nullptr, out, nullptr,
                                                HID_, HID_, 0, 0);
}

// Round 3
// 333.535 us; speedup vs baseline: 4.6333x; 2.5166x over previous
//
#include <hip/hip_runtime.h>
#include <math.h>

#define B_    2
#define S_    1024
#define HID_  2048
#define NH_   16
#define NKV_  4
#define HD_   128
#define GROUPS (NH_ / NKV_)
#define SCALE_ 0.08838834764831845f   // 1/sqrt(128)

typedef _Float16 f16x8 __attribute__((ext_vector_type(8)));
typedef float    f32x4 __attribute__((ext_vector_type(4)));

// ---------------------------------------------------------------------------
// f32 -> f16 cast, 4 elems/thread
// ---------------------------------------------------------------------------
__global__ __launch_bounds__(256) void cast_f16(
    const float4* __restrict__ x, ushort4* __restrict__ y, int n4)
{
    int i = blockIdx.x * 256 + threadIdx.x;
    if (i >= n4) return;
    float4 v = x[i];
    _Float16 a = (_Float16)v.x, b = (_Float16)v.y,
             c = (_Float16)v.z, d = (_Float16)v.w;
    ushort4 o;
    o.x = *(unsigned short*)&a; o.y = *(unsigned short*)&b;
    o.z = *(unsigned short*)&c; o.w = *(unsigned short*)&d;
    y[i] = o;
}

// ---------------------------------------------------------------------------
// f16 MFMA GEMM: C[m,n] = sum_k A[m,k] * W[n,k], f32 accumulate.
// 128x128 tile, BK=32, 256 threads = 4 waves.
// mode 0: C[m*N+n] f32
// mode 1: scatter f32 to (b,h,s,d): h=n>>7, d=n&127, b=m>>10, s=m&1023
// mode 2: fused K|V: bn<512 -> K part, f32 scatter to C; else V part,
//         f16 scatter to C2h. heads applies to both (NKV).
// ---------------------------------------------------------------------------
__global__ __launch_bounds__(256) void gemm_mfma(
    const _Float16* __restrict__ A,
    const _Float16* __restrict__ W,
    const _Float16* __restrict__ W2,
    float* __restrict__ C, _Float16* __restrict__ C2h,
    int K, int N, int mode, int heads)
{
    __shared__ __align__(16) _Float16 As[128][32];
    __shared__ __align__(16) _Float16 Ws[128][32];

    const int tid  = threadIdx.x;
    const int lane = tid & 63, wave = tid >> 6;
    const int wr = (wave >> 1) * 64, wc = (wave & 1) * 64;
    const int bm = blockIdx.y * 128;
    int bn = blockIdx.x * 128;

    const _Float16* Wp = W;
    bool vpart = false;
    if (mode == 2 && bn >= 512) { Wp = W2; vpart = true; bn -= 512; }

    const int r0 = tid >> 2, c0 = (tid & 3) * 8;
    const _Float16* Ag0 = A  + (size_t)(bm + r0)      * K + c0;
    const _Float16* Ag1 = A  + (size_t)(bm + r0 + 64) * K + c0;
    const _Float16* Wg0 = Wp + (size_t)(bn + r0)      * K + c0;
    const _Float16* Wg1 = Wp + (size_t)(bn + r0 + 64) * K + c0;

    f32x4 acc[4][4];
    const f32x4 fz = {0.f, 0.f, 0.f, 0.f};
#pragma unroll
    for (int i = 0; i < 4; i++)
#pragma unroll
        for (int j = 0; j < 4; j++) acc[i][j] = fz;

    const int ml = lane & 15, kg = lane >> 4;

    for (int k0 = 0; k0 < K; k0 += 32) {
        f16x8 av0 = *(const f16x8*)(Ag0 + k0);
        f16x8 av1 = *(const f16x8*)(Ag1 + k0);
        f16x8 wv0 = *(const f16x8*)(Wg0 + k0);
        f16x8 wv1 = *(const f16x8*)(Wg1 + k0);
        __syncthreads();
        *(f16x8*)&As[r0][c0]      = av0;
        *(f16x8*)&As[r0 + 64][c0] = av1;
        *(f16x8*)&Ws[r0][c0]      = wv0;
        *(f16x8*)&Ws[r0 + 64][c0] = wv1;
        __syncthreads();

        f16x8 a[4], b[4];
#pragma unroll
        for (int mi = 0; mi < 4; mi++)
            a[mi] = *(const f16x8*)&As[wr + mi * 16 + ml][kg * 8];
#pragma unroll
        for (int ni = 0; ni < 4; ni++)
            b[ni] = *(const f16x8*)&Ws[wc + ni * 16 + ml][kg * 8];
#pragma unroll
        for (int mi = 0; mi < 4; mi++)
#pragma unroll
            for (int ni = 0; ni < 4; ni++)
                acc[mi][ni] = __builtin_amdgcn_mfma_f32_16x16x32_f16(
                    a[mi], b[ni], acc[mi][ni], 0, 0, 0);
    }

#pragma unroll
    for (int mi = 0; mi < 4; mi++) {
#pragma unroll
        for (int ni = 0; ni < 4; ni++) {
#pragma unroll
            for (int r = 0; r < 4; r++) {
                int m = bm + wr + mi * 16 + kg * 4 + r;
                int n = bn + wc + ni * 16 + ml;
                float v = acc[mi][ni][r];
                if (mode == 0) {
                    C[(size_t)m * N + n] = v;
                } else {
                    int hh = n >> 7, d = n & 127;
                    int b_ = m >> 10, s = m & 1023;
                    size_t idx = (((size_t)(b_ * heads + hh)) * S_ + s) * HD_ + d;
                    if (vpart) C2h[idx] = (_Float16)v;
                    else       C[idx] = v;
                }
            }
        }
    }
}

// ---------------------------------------------------------------------------
// Fused RoPE + RMSNorm: read f32 (b,H,s,d) rows, write f16 same layout.
// ---------------------------------------------------------------------------
__global__ __launch_bounds__(256) void rope_rms_f16(
    const float* __restrict__ x, const float* __restrict__ w,
    _Float16* __restrict__ out, int nrows)
{
    int row = blockIdx.x * 4 + (threadIdx.x >> 6);
    int lane = threadIdx.x & 63;
    if (row >= nrows) return;
    int s = row & (S_ - 1);

    const float* p = x + (size_t)row * HD_;
    float x1 = p[lane], x2 = p[lane + 64];

    float invf = exp2f(-(float)lane * 0.2076205059304601f);
    float ang = (float)s * invf;
    float c, sn;
    sincosf(ang, &sn, &c);

    float y1 = x1 * c - x2 * sn;
    float y2 = x1 * sn + x2 * c;

    float ss = y1 * y1 + y2 * y2;
#pragma unroll
    for (int off = 32; off > 0; off >>= 1) ss += __shfl_xor(ss, off);

    float scl = rsqrtf(ss * (1.0f / 128.0f) + 1e-6f);
    _Float16* q = out + (size_t)row * HD_;
    q[lane]      = (_Float16)(y1 * scl * w[lane]);
    q[lane + 64] = (_Float16)(y2 * scl * w[lane + 64]);
}

// ---------------------------------------------------------------------------
// MFMA stick-breaking attention. BQ=BK=64, 512 threads (8 waves).
// Grid (8, NH, B): block handles paired query tiles {p, 15-p} -> 17 k-iters.
// QK^T: wave (qw = wave>>1) strip of 16 q, (kh = wave&1) half of 32 keys.
// PV:   wave strip of 16 q, kh-half of 64 d.
// Output f16 in (b, s, h, d).
// ---------------------------------------------------------------------------
#define QK_STR 136   // f16 row stride for Qs/Ks (272 B, 16B-aligned)
#define VT_STR 72    // f16 row stride for Vt  (144 B, 16B-aligned)
#define SS_STR 68    // f32 row stride for Ss  (272 B, 16B-aligned)
#define AT_STR 72    // f16 row stride for atts

__global__ __launch_bounds__(512) void stick_attn(
    const _Float16* __restrict__ Q, const _Float16* __restrict__ K,
    const _Float16* __restrict__ V, _Float16* __restrict__ AO)
{
    __shared__ __align__(16) _Float16 Qs[64][QK_STR];
    __shared__ __align__(16) _Float16 Ks[64][QK_STR];
    __shared__ __align__(16) _Float16 Vt[128][VT_STR];
    __shared__ __align__(16) float    Ss[64][SS_STR];
    __shared__ __align__(16) _Float16 atts[64][AT_STR];
    __shared__ float accs[64];

    const int pairIdx = blockIdx.x;           // 0..7
    const int h = blockIdx.y, b = blockIdx.z;
    const int kvh = h / GROUPS;
    const int tid = threadIdx.x;
    const int lane = tid & 63, wave = tid >> 6;
    const int qw = wave >> 1;                  // 0..3: query strip
    const int kh = wave & 1;                   // key/d half
    const int ml = lane & 15, quad = lane >> 4;

    const _Float16* Kbase = K + ((size_t)(b * NKV_ + kvh) * S_) * HD_;
    const _Float16* Vbase = V + ((size_t)(b * NKV_ + kvh) * S_) * HD_;

    const f32x4 fz = {0.f, 0.f, 0.f, 0.f};

    for (int rep = 0; rep < 2; rep++) {
        const int qb = (rep == 0) ? pairIdx : 15 - pairIdx;
        const int qi0 = qb * 64;
        const _Float16* Qbase = Q + ((size_t)(b * NH_ + h) * S_ + qi0) * HD_;

        __syncthreads();   // prior rep's LDS reads done
        for (int idx = tid; idx < 64 * 16; idx += 512) {
            int r = idx >> 4, c8 = (idx & 15) * 8;
            *(f16x8*)&Qs[r][c8] = *(const f16x8*)(Qbase + r * HD_ + c8);
        }
        if (tid < 64) accs[tid] = 0.f;
        __syncthreads();

        // hoist Q A-frags for this wave's strip
        f16x8 aq[4];
#pragma unroll
        for (int ks = 0; ks < 4; ks++)
            aq[ks] = *(const f16x8*)&Qs[qw * 16 + ml][ks * 32 + quad * 8];

        f32x4 accO[4] = {fz, fz, fz, fz};

        for (int kb = qb; kb >= 0; --kb) {
            __syncthreads();   // prev PV reads of atts/Vt + scan reads of Ss done

            // stage K tile (coalesced)
            for (int idx = tid; idx < 64 * 16; idx += 512) {
                int r = idx >> 4, c8 = (idx & 15) * 8;
                *(f16x8*)&Ks[r][c8] =
                    *(const f16x8*)(Kbase + (size_t)(kb * 64 + r) * HD_ + c8);
            }
            // stage V transposed: wave w owns d-range [w*16, w*16+16), key = lane
            {
                int key = lane, dg = wave;
                const _Float16* vp =
                    Vbase + (size_t)(kb * 64 + key) * HD_ + dg * 16;
                f16x8 v0 = *(const f16x8*)(vp);
                f16x8 v1 = *(const f16x8*)(vp + 8);
#pragma unroll
                for (int i = 0; i < 8; i++) {
                    Vt[dg * 16 + i][key]     = v0[i];
                    Vt[dg * 16 + 8 + i][key] = v1[i];
                }
            }
            __syncthreads();

            // QK^T -> Ss (scaled)
            f32x4 accS[2] = {fz, fz};
#pragma unroll
            for (int ks = 0; ks < 4; ks++) {
#pragma unroll
                for (int ni = 0; ni < 2; ni++) {
                    f16x8 bf = *(const f16x8*)
                        &Ks[kh * 32 + ni * 16 + ml][ks * 32 + quad * 8];
                    accS[ni] = __builtin_amdgcn_mfma_f32_16x16x32_f16(
                        aq[ks], bf, accS[ni], 0, 0, 0);
                }
            }
#pragma unroll
            for (int ni = 0; ni < 2; ni++)
#pragma unroll
                for (int r = 0; r < 4; r++)
                    Ss[qw * 16 + quad * 4 + r][kh * 32 + ni * 16 + ml] =
                        accS[ni][r] * SCALE_;
            __syncthreads();

            // fused logsig + suffix-scan + att (8 threads per query row)
            {
                int q = tid >> 3, seg = tid & 7;
                int qg = qi0 + q;
                int j0 = kb * 64 + seg * 8;
                float4 s0 = *(float4*)&Ss[q][seg * 8];
                float4 s1 = *(float4*)&Ss[q][seg * 8 + 4];
                float L[8] = {s0.x, s0.y, s0.z, s0.w, s1.x, s1.y, s1.z, s1.w};
                float lp[8], lo[8];
#pragma unroll
                for (int i = 0; i < 8; i++) {
                    float l = L[i];
                    float e = __expf(-fabsf(l));
                    float lg = __logf(1.f + e);
                    lp[i] = fminf(l, 0.f) - lg;
                    lo[i] = (j0 + i < qg) ? (fminf(-l, 0.f) - lg) : 0.f;
                }
                float suf = 0.f;
#pragma unroll
                for (int i = 7; i >= 0; --i) {
                    float cur = lo[i]; lo[i] = suf; suf += cur;
                }
                // inclusive suffix-scan of segment totals across 8 lanes
                float x = suf;
#pragma unroll
                for (int off = 1; off < 8; off <<= 1) {
                    float y = __shfl_down(x, off);
                    if (seg + off < 8) x += y;
                }
                float base = x - suf;            // strictly-later segments
                float accq = accs[q];            // suffix from later k-blocks
                f16x8 av;
#pragma unroll
                for (int i = 0; i < 8; i++) {
                    float a = (j0 + i < qg)
                        ? __expf(lp[i] + lo[i] + base + accq) : 0.f;
                    av[i] = (_Float16)a;
                }
                *(f16x8*)&atts[q][seg * 8] = av;
                if (seg == 0) accs[q] = accq + x; // same-wave: reads precede
            }
            __syncthreads();

            // PV: O[q][d] += att[q][k] * V[k][d]
#pragma unroll
            for (int ks = 0; ks < 2; ks++) {
                f16x8 ap = *(const f16x8*)&atts[qw * 16 + ml][ks * 32 + quad * 8];
#pragma unroll
                for (int ni = 0; ni < 4; ni++) {
                    f16x8 bv = *(const f16x8*)
                        &Vt[kh * 64 + ni * 16 + ml][ks * 32 + quad * 8];
                    accO[ni] = __builtin_amdgcn_mfma_f32_16x16x32_f16(
                        ap, bv, accO[ni], 0, 0, 0);
                }
            }
        }

        // write O tile: (b, s, h, d) f16
#pragma unroll
        for (int ni = 0; ni < 4; ni++) {
#pragma unroll
            for (int r = 0; r < 4; r++) {
                int qg = qi0 + qw * 16 + quad * 4 + r;
                int d = kh * 64 + ni * 16 + ml;
                AO[((size_t)(b * S_ + qg) * NH_ + h) * HD_ + d] =
                    (_Float16)accO[ni][r];
            }
        }
    }
}

// ---------------------------------------------------------------------------
extern "C" void kernel_launch(void* const* d_in, const int* in_sizes, int n_in,
                              void* d_out, int out_size, void* d_ws, size_t ws_size,
                              hipStream_t stream)
{
    const float* hs = (const float*)d_in[0];
    const float* Wq = (const float*)d_in[1];
    const float* Wk = (const float*)d_in[2];
    const float* Wv = (const float*)d_in[3];
    const float* Wo = (const float*)d_in[4];
    const float* qw = (const float*)d_in[5];
    const float* kw = (const float*)d_in[6];
    float* out = (float*)d_out;

    // f32 region
    float* q_ws = (float*)d_ws;                 // 4,194,304 f
    float* k_ws = q_ws + 4194304;               // 1,048,576 f
    // f16 region
    _Float16* hsh = (_Float16*)(k_ws + 1048576);
    _Float16* Wqh = hsh + 4194304;
    _Float16* Wkh = Wqh + 4194304;
    _Float16* Wvh = Wkh + 1048576;
    _Float16* Qh  = Wvh + 1048576;              // 4,194,304
    _Float16* Kh  = Qh + 4194304;               // 1,048,576
    _Float16* Vh  = Kh + 1048576;               // 1,048,576
    // aliases (stream-ordered reuse)
    _Float16* AOh = hsh;   // attention out, after hs no longer needed
    _Float16* Woh = Wqh;   // Wo cast, after Q projection done

    dim3 blk(256);

    cast_f16<<<4096, blk, 0, stream>>>((const float4*)hs, (ushort4*)hsh, 1048576);
    cast_f16<<<4096, blk, 0, stream>>>((const float4*)Wq, (ushort4*)Wqh, 1048576);
    cast_f16<<<1024, blk, 0, stream>>>((const float4*)Wk, (ushort4*)Wkh, 262144);
    cast_f16<<<1024, blk, 0, stream>>>((const float4*)Wv, (ushort4*)Wvh, 262144);

    // Q projection -> f32 (b,h,s,d); K|V fused: K -> f32, V -> f16 direct
    gemm_mfma<<<dim3(16, 16), blk, 0, stream>>>(hsh, Wqh, nullptr, q_ws, nullptr,
                                                HID_, 0, 1, NH_);
    gemm_mfma<<<dim3(8, 16), blk, 0, stream>>>(hsh, Wkh, Wvh, k_ws, Vh,
                                               HID_, 0, 2, NKV_);

    // Wo cast (reuses Wqh space — Q projection already launched)
    cast_f16<<<4096, blk, 0, stream>>>((const float4*)Wo, (ushort4*)Woh, 1048576);

    // RoPE + RMSNorm -> f16
    rope_rms_f16<<<dim3(B_ * NH_ * S_ / 4), blk, 0, stream>>>(q_ws, qw, Qh,
                                                              B_ * NH_ * S_);
    rope_rms_f16<<<dim3(B_ * NKV_ * S_ / 4), blk, 0, stream>>>(k_ws, kw, Kh,
                                                               B_ * NKV_ * S_);

    // stick-breaking attention -> f16 (b,s,h,d)
    stick_attn<<<dim3(8, NH_, B_), dim3(512), 0, stream>>>(Qh, Kh, Vh, AOh);

    // output projection
    gemm_mfma<<<dim3(16, 16), blk, 0, stream>>>(AOh, Woh, nullptr, out, nullptr,
                                                HID_, HID_, 0, 0);
}

// Round 4
// 276.863 us; speedup vs baseline: 5.5817x; 1.2047x over previous
//
#include <hip/hip_runtime.h>
#include <math.h>

#define B_    2
#define S_    1024
#define HID_  2048
#define NH_   16
#define NKV_  4
#define HD_   128
#define GROUPS (NH_ / NKV_)
#define SCALE_ 0.08838834764831845f   // 1/sqrt(128)

typedef _Float16 f16x8 __attribute__((ext_vector_type(8)));
typedef float    f32x4 __attribute__((ext_vector_type(4)));

// async global->LDS, 16B per lane; LDS dest = base + lane*16 (wave-uniform base)
__device__ __forceinline__ void async_copy16(const void* g, void* l) {
    __builtin_amdgcn_global_load_lds(
        (const __attribute__((address_space(1))) void*)g,
        (__attribute__((address_space(3))) void*)l, 16, 0, 0);
}

// ---------------------------------------------------------------------------
// fused f32 -> f16 cast over 4 tensors
// ---------------------------------------------------------------------------
__global__ __launch_bounds__(256) void cast4_f16(
    const float4* __restrict__ s0, ushort4* __restrict__ d0, int n0,
    const float4* __restrict__ s1, ushort4* __restrict__ d1, int n1,
    const float4* __restrict__ s2, ushort4* __restrict__ d2, int n2,
    const float4* __restrict__ s3, ushort4* __restrict__ d3, int n3)
{
    int i = blockIdx.x * 256 + threadIdx.x;
    const float4* s; ushort4* d; int idx;
    if (i < n0)                { s = s0; d = d0; idx = i; }
    else if (i < n0 + n1)      { s = s1; d = d1; idx = i - n0; }
    else if (i < n0 + n1 + n2) { s = s2; d = d2; idx = i - n0 - n1; }
    else if (i < n0 + n1 + n2 + n3) { s = s3; d = d3; idx = i - n0 - n1 - n2; }
    else return;
    float4 v = s[idx];
    _Float16 a = (_Float16)v.x, b = (_Float16)v.y,
             c = (_Float16)v.z, e = (_Float16)v.w;
    ushort4 o;
    o.x = *(unsigned short*)&a; o.y = *(unsigned short*)&b;
    o.z = *(unsigned short*)&c; o.w = *(unsigned short*)&e;
    d[idx] = o;
}

__global__ __launch_bounds__(256) void cast_f16(
    const float4* __restrict__ x, ushort4* __restrict__ y, int n4)
{
    int i = blockIdx.x * 256 + threadIdx.x;
    if (i >= n4) return;
    float4 v = x[i];
    _Float16 a = (_Float16)v.x, b = (_Float16)v.y,
             c = (_Float16)v.z, e = (_Float16)v.w;
    ushort4 o;
    o.x = *(unsigned short*)&a; o.y = *(unsigned short*)&b;
    o.z = *(unsigned short*)&c; o.w = *(unsigned short*)&e;
    y[i] = o;
}

// ---------------------------------------------------------------------------
// Fused QKV GEMM (m97-style staging). Grid (24, 16), 256 thr = 4 waves.
// bt<16: Q tile -> q_f32 scatter (b,h,s,d), heads=16
// bt 16..19: K tile -> k_f32 scatter, heads=4
// bt 20..23: V tile -> v_f16 scatter, heads=4
// C = A(2048xK) * W^T, K=2048, 128x128 tile, BK=32.
// ---------------------------------------------------------------------------
__global__ __launch_bounds__(256) void qkv_gemm(
    const _Float16* __restrict__ A,
    const _Float16* __restrict__ Wq,
    const _Float16* __restrict__ Wk,
    const _Float16* __restrict__ Wv,
    float* __restrict__ Cq, float* __restrict__ Ck,
    _Float16* __restrict__ Cv)
{
    __shared__ __align__(16) _Float16 As[128][32];
    __shared__ __align__(16) _Float16 Ws[128][32];

    const int tid  = threadIdx.x;
    const int lane = tid & 63, wave = tid >> 6;
    const int wr = (wave >> 1) * 64, wc = (wave & 1) * 64;
    const int bm = blockIdx.y * 128;
    const int bt = blockIdx.x;

    const _Float16* Wsel;
    int nrow0, heads;
    bool vout = false;
    if (bt < 16)      { Wsel = Wq; nrow0 = bt * 128;        heads = NH_;  }
    else if (bt < 20) { Wsel = Wk; nrow0 = (bt - 16) * 128; heads = NKV_; }
    else              { Wsel = Wv; nrow0 = (bt - 20) * 128; heads = NKV_; vout = true; }

    const int srow = 32 * wave + (lane >> 2);
    const int scol = (lane & 3) * 8;
    const _Float16* Ag = A    + (size_t)(bm + srow)    * HID_ + scol;
    const _Float16* Wg = Wsel + (size_t)(nrow0 + srow) * HID_ + scol;
    _Float16* lA = &As[32 * wave][0];
    _Float16* lW = &Ws[32 * wave][0];

    f32x4 acc[4][4];
    const f32x4 fz = {0.f, 0.f, 0.f, 0.f};
#pragma unroll
    for (int i = 0; i < 4; i++)
#pragma unroll
        for (int j = 0; j < 4; j++) acc[i][j] = fz;

    const int ml = lane & 15, kg = lane >> 4;

    for (int k0 = 0; k0 < HID_; k0 += 32) {
        __syncthreads();
        async_copy16(Ag + k0, lA);
        async_copy16(Ag + k0 + (size_t)16 * HID_, lA + 16 * 32);
        async_copy16(Wg + k0, lW);
        async_copy16(Wg + k0 + (size_t)16 * HID_, lW + 16 * 32);
        __syncthreads();

        f16x8 a[4], b[4];
#pragma unroll
        for (int mi = 0; mi < 4; mi++)
            a[mi] = *(const f16x8*)&As[wr + mi * 16 + ml][kg * 8];
#pragma unroll
        for (int ni = 0; ni < 4; ni++)
            b[ni] = *(const f16x8*)&Ws[wc + ni * 16 + ml][kg * 8];
#pragma unroll
        for (int mi = 0; mi < 4; mi++)
#pragma unroll
            for (int ni = 0; ni < 4; ni++)
                acc[mi][ni] = __builtin_amdgcn_mfma_f32_16x16x32_f16(
                    a[mi], b[ni], acc[mi][ni], 0, 0, 0);
    }

#pragma unroll
    for (int mi = 0; mi < 4; mi++) {
#pragma unroll
        for (int ni = 0; ni < 4; ni++) {
#pragma unroll
            for (int r = 0; r < 4; r++) {
                int m = bm + wr + mi * 16 + kg * 4 + r;
                int n = nrow0 + wc + ni * 16 + ml;
                int hh = n >> 7, d = n & 127;
                int b_ = m >> 10, s = m & 1023;
                size_t idx = (((size_t)(b_ * heads + hh)) * S_ + s) * HD_ + d;
                float v = acc[mi][ni][r];
                if (vout) Cv[idx] = (_Float16)v;
                else if (bt < 16) Cq[idx] = v;
                else Ck[idx] = v;
            }
        }
    }
}

// ---------------------------------------------------------------------------
// Output GEMM: C[m*2048+n] f32 = AO(2048x2048 f16) * Wo^T. Grid (16,16).
// ---------------------------------------------------------------------------
__global__ __launch_bounds__(256) void out_gemm(
    const _Float16* __restrict__ A,
    const _Float16* __restrict__ W,
    float* __restrict__ C)
{
    __shared__ __align__(16) _Float16 As[128][32];
    __shared__ __align__(16) _Float16 Ws[128][32];

    const int tid  = threadIdx.x;
    const int lane = tid & 63, wave = tid >> 6;
    const int wr = (wave >> 1) * 64, wc = (wave & 1) * 64;
    const int bm = blockIdx.y * 128, bn = blockIdx.x * 128;

    const int srow = 32 * wave + (lane >> 2);
    const int scol = (lane & 3) * 8;
    const _Float16* Ag = A + (size_t)(bm + srow) * HID_ + scol;
    const _Float16* Wg = W + (size_t)(bn + srow) * HID_ + scol;
    _Float16* lA = &As[32 * wave][0];
    _Float16* lW = &Ws[32 * wave][0];

    f32x4 acc[4][4];
    const f32x4 fz = {0.f, 0.f, 0.f, 0.f};
#pragma unroll
    for (int i = 0; i < 4; i++)
#pragma unroll
        for (int j = 0; j < 4; j++) acc[i][j] = fz;

    const int ml = lane & 15, kg = lane >> 4;

    for (int k0 = 0; k0 < HID_; k0 += 32) {
        __syncthreads();
        async_copy16(Ag + k0, lA);
        async_copy16(Ag + k0 + (size_t)16 * HID_, lA + 16 * 32);
        async_copy16(Wg + k0, lW);
        async_copy16(Wg + k0 + (size_t)16 * HID_, lW + 16 * 32);
        __syncthreads();

        f16x8 a[4], b[4];
#pragma unroll
        for (int mi = 0; mi < 4; mi++)
            a[mi] = *(const f16x8*)&As[wr + mi * 16 + ml][kg * 8];
#pragma unroll
        for (int ni = 0; ni < 4; ni++)
            b[ni] = *(const f16x8*)&Ws[wc + ni * 16 + ml][kg * 8];
#pragma unroll
        for (int mi = 0; mi < 4; mi++)
#pragma unroll
            for (int ni = 0; ni < 4; ni++)
                acc[mi][ni] = __builtin_amdgcn_mfma_f32_16x16x32_f16(
                    a[mi], b[ni], acc[mi][ni], 0, 0, 0);
    }

#pragma unroll
    for (int mi = 0; mi < 4; mi++)
#pragma unroll
        for (int ni = 0; ni < 4; ni++)
#pragma unroll
            for (int r = 0; r < 4; r++) {
                int m = bm + wr + mi * 16 + kg * 4 + r;
                int n = bn + wc + ni * 16 + ml;
                C[(size_t)m * HID_ + n] = acc[mi][ni][r];
            }
}

// ---------------------------------------------------------------------------
// Fused RoPE + RMSNorm: read f32 (b,H,s,d) rows, write f16 same layout.
// ---------------------------------------------------------------------------
__global__ __launch_bounds__(256) void rope_rms_f16(
    const float* __restrict__ x, const float* __restrict__ w,
    _Float16* __restrict__ out, int nrows)
{
    int row = blockIdx.x * 4 + (threadIdx.x >> 6);
    int lane = threadIdx.x & 63;
    if (row >= nrows) return;
    int s = row & (S_ - 1);

    const float* p = x + (size_t)row * HD_;
    float x1 = p[lane], x2 = p[lane + 64];

    float invf = exp2f(-(float)lane * 0.2076205059304601f);
    float ang = (float)s * invf;
    float c, sn;
    sincosf(ang, &sn, &c);

    float y1 = x1 * c - x2 * sn;
    float y2 = x1 * sn + x2 * c;

    float ss = y1 * y1 + y2 * y2;
#pragma unroll
    for (int off = 32; off > 0; off >>= 1) ss += __shfl_xor(ss, off);

    float scl = rsqrtf(ss * (1.0f / 128.0f) + 1e-6f);
    _Float16* q = out + (size_t)row * HD_;
    q[lane]      = (_Float16)(y1 * scl * w[lane]);
    q[lane + 64] = (_Float16)(y2 * scl * w[lane + 64]);
}

// ---------------------------------------------------------------------------
// MFMA stick-breaking attention. BQ=BK=64, 512 threads (8 waves).
// Grid (16, NH, B) = 512 blocks -> 2 blocks/CU co-residency.
// ---------------------------------------------------------------------------
#define QK_STR 136
#define VT_STR 72
#define SS_STR 68
#define AT_STR 72

__global__ __launch_bounds__(512) void stick_attn(
    const _Float16* __restrict__ Q, const _Float16* __restrict__ K,
    const _Float16* __restrict__ V, _Float16* __restrict__ AO)
{
    __shared__ __align__(16) _Float16 Qs[64][QK_STR];
    __shared__ __align__(16) _Float16 Ks[64][QK_STR];
    __shared__ __align__(16) _Float16 Vt[128][VT_STR];
    __shared__ __align__(16) float    Ss[64][SS_STR];
    __shared__ __align__(16) _Float16 atts[64][AT_STR];
    __shared__ float accs[64];

    const int qb = blockIdx.x;
    const int h = blockIdx.y, b = blockIdx.z;
    const int kvh = h / GROUPS;
    const int tid = threadIdx.x;
    const int lane = tid & 63, wave = tid >> 6;
    const int qw = wave >> 1;
    const int kh = wave & 1;
    const int ml = lane & 15, quad = lane >> 4;

    const _Float16* Kbase = K + ((size_t)(b * NKV_ + kvh) * S_) * HD_;
    const _Float16* Vbase = V + ((size_t)(b * NKV_ + kvh) * S_) * HD_;

    const f32x4 fz = {0.f, 0.f, 0.f, 0.f};

    const int qi0 = qb * 64;
    const _Float16* Qbase = Q + ((size_t)(b * NH_ + h) * S_ + qi0) * HD_;

    for (int idx = tid; idx < 64 * 16; idx += 512) {
        int r = idx >> 4, c8 = (idx & 15) * 8;
        *(f16x8*)&Qs[r][c8] = *(const f16x8*)(Qbase + r * HD_ + c8);
    }
    if (tid < 64) accs[tid] = 0.f;
    __syncthreads();

    f16x8 aq[4];
#pragma unroll
    for (int ks = 0; ks < 4; ks++)
        aq[ks] = *(const f16x8*)&Qs[qw * 16 + ml][ks * 32 + quad * 8];

    f32x4 accO[4] = {fz, fz, fz, fz};

    for (int kb = qb; kb >= 0; --kb) {
        __syncthreads();

        for (int idx = tid; idx < 64 * 16; idx += 512) {
            int r = idx >> 4, c8 = (idx & 15) * 8;
            *(f16x8*)&Ks[r][c8] =
                *(const f16x8*)(Kbase + (size_t)(kb * 64 + r) * HD_ + c8);
        }
        {
            int key = lane, dg = wave;
            const _Float16* vp =
                Vbase + (size_t)(kb * 64 + key) * HD_ + dg * 16;
            f16x8 v0 = *(const f16x8*)(vp);
            f16x8 v1 = *(const f16x8*)(vp + 8);
#pragma unroll
            for (int i = 0; i < 8; i++) {
                Vt[dg * 16 + i][key]     = v0[i];
                Vt[dg * 16 + 8 + i][key] = v1[i];
            }
        }
        __syncthreads();

        f32x4 accS[2] = {fz, fz};
#pragma unroll
        for (int ks = 0; ks < 4; ks++) {
#pragma unroll
            for (int ni = 0; ni < 2; ni++) {
                f16x8 bf = *(const f16x8*)
                    &Ks[kh * 32 + ni * 16 + ml][ks * 32 + quad * 8];
                accS[ni] = __builtin_amdgcn_mfma_f32_16x16x32_f16(
                    aq[ks], bf, accS[ni], 0, 0, 0);
            }
        }
#pragma unroll
        for (int ni = 0; ni < 2; ni++)
#pragma unroll
            for (int r = 0; r < 4; r++)
                Ss[qw * 16 + quad * 4 + r][kh * 32 + ni * 16 + ml] =
                    accS[ni][r] * SCALE_;
        __syncthreads();

        {
            int q = tid >> 3, seg = tid & 7;
            int qg = qi0 + q;
            int j0 = kb * 64 + seg * 8;
            float4 s0 = *(float4*)&Ss[q][seg * 8];
            float4 s1 = *(float4*)&Ss[q][seg * 8 + 4];
            float L[8] = {s0.x, s0.y, s0.z, s0.w, s1.x, s1.y, s1.z, s1.w};
            float lp[8], lo[8];
#pragma unroll
            for (int i = 0; i < 8; i++) {
                float l = L[i];
                float e = __expf(-fabsf(l));
                float lg = __logf(1.f + e);
                lp[i] = fminf(l, 0.f) - lg;
                lo[i] = (j0 + i < qg) ? (fminf(-l, 0.f) - lg) : 0.f;
            }
            float suf = 0.f;
#pragma unroll
            for (int i = 7; i >= 0; --i) {
                float cur = lo[i]; lo[i] = suf; suf += cur;
            }
            float x = suf;
#pragma unroll
            for (int off = 1; off < 8; off <<= 1) {
                float y = __shfl_down(x, off);
                if (seg + off < 8) x += y;
            }
            float base = x - suf;
            float accq = accs[q];
            f16x8 av;
#pragma unroll
            for (int i = 0; i < 8; i++) {
                float a = (j0 + i < qg)
                    ? __expf(lp[i] + lo[i] + base + accq) : 0.f;
                av[i] = (_Float16)a;
            }
            *(f16x8*)&atts[q][seg * 8] = av;
            if (seg == 0) accs[q] = accq + x;
        }
        __syncthreads();

#pragma unroll
        for (int ks = 0; ks < 2; ks++) {
            f16x8 ap = *(const f16x8*)&atts[qw * 16 + ml][ks * 32 + quad * 8];
#pragma unroll
            for (int ni = 0; ni < 4; ni++) {
                f16x8 bv = *(const f16x8*)
                    &Vt[kh * 64 + ni * 16 + ml][ks * 32 + quad * 8];
                accO[ni] = __builtin_amdgcn_mfma_f32_16x16x32_f16(
                    ap, bv, accO[ni], 0, 0, 0);
            }
        }
    }

#pragma unroll
    for (int ni = 0; ni < 4; ni++) {
#pragma unroll
        for (int r = 0; r < 4; r++) {
            int qg = qi0 + qw * 16 + quad * 4 + r;
            int d = kh * 64 + ni * 16 + ml;
            AO[((size_t)(b * S_ + qg) * NH_ + h) * HD_ + d] =
                (_Float16)accO[ni][r];
        }
    }
}

// ---------------------------------------------------------------------------
extern "C" void kernel_launch(void* const* d_in, const int* in_sizes, int n_in,
                              void* d_out, int out_size, void* d_ws, size_t ws_size,
                              hipStream_t stream)
{
    const float* hs = (const float*)d_in[0];
    const float* Wq = (const float*)d_in[1];
    const float* Wk = (const float*)d_in[2];
    const float* Wv = (const float*)d_in[3];
    const float* Wo = (const float*)d_in[4];
    const float* qw = (const float*)d_in[5];
    const float* kw = (const float*)d_in[6];
    float* out = (float*)d_out;

    // f32 region
    float* q_ws = (float*)d_ws;                 // 4,194,304 f
    float* k_ws = q_ws + 4194304;               // 1,048,576 f
    // f16 region
    _Float16* hsh = (_Float16*)(k_ws + 1048576);
    _Float16* Wqh = hsh + 4194304;
    _Float16* Wkh = Wqh + 4194304;
    _Float16* Wvh = Wkh + 1048576;
    _Float16* Qh  = Wvh + 1048576;              // 4,194,304
    _Float16* Kh  = Qh + 4194304;               // 1,048,576
    _Float16* Vh  = Kh + 1048576;               // 1,048,576
    // stream-ordered aliases
    _Float16* AOh = hsh;   // after QKV gemm consumed hs
    _Float16* Woh = Wqh;   // after QKV gemm consumed Wq

    dim3 blk(256);

    // fused input casts: hs | Wq | Wk | Wv
    cast4_f16<<<10240, blk, 0, stream>>>(
        (const float4*)hs, (ushort4*)hsh, 1048576,
        (const float4*)Wq, (ushort4*)Wqh, 1048576,
        (const float4*)Wk, (ushort4*)Wkh, 262144,
        (const float4*)Wv, (ushort4*)Wvh, 262144);

    // fused QKV projection: Q,K -> f32 (b,h,s,d); V -> f16 direct
    qkv_gemm<<<dim3(24, 16), blk, 0, stream>>>(hsh, Wqh, Wkh, Wvh,
                                               q_ws, k_ws, Vh);

    // Wo cast (reuses Wq's f16 buffer)
    cast_f16<<<4096, blk, 0, stream>>>((const float4*)Wo, (ushort4*)Woh, 1048576);

    // RoPE + RMSNorm -> f16
    rope_rms_f16<<<dim3(B_ * NH_ * S_ / 4), blk, 0, stream>>>(q_ws, qw, Qh,
                                                              B_ * NH_ * S_);
    rope_rms_f16<<<dim3(B_ * NKV_ * S_ / 4), blk, 0, stream>>>(k_ws, kw, Kh,
                                                               B_ * NKV_ * S_);

    // stick-breaking attention -> f16 (b,s,h,d)
    stick_attn<<<dim3(16, NH_, B_), dim3(512), 0, stream>>>(Qh, Kh, Vh, AOh);

    // output projection
    out_gemm<<<dim3(16, 16), blk, 0, stream>>>(AOh, Woh, out);
}

// Round 5
// 248.698 us; speedup vs baseline: 6.2138x; 1.1132x over previous
//
#include <hip/hip_runtime.h>
#include <math.h>

#define B_    2
#define S_    1024
#define HID_  2048
#define NH_   16
#define NKV_  4
#define HD_   128
#define GROUPS (NH_ / NKV_)
#define SCALE_ 0.08838834764831845f   // 1/sqrt(128)

typedef _Float16 f16x8 __attribute__((ext_vector_type(8)));
typedef float    f32x4 __attribute__((ext_vector_type(4)));

// async global->LDS, 16B per lane; LDS dest = base + lane*16 (wave-uniform base)
__device__ __forceinline__ void async_copy16(const void* g, void* l) {
    __builtin_amdgcn_global_load_lds(
        (const __attribute__((address_space(1))) void*)g,
        (__attribute__((address_space(3))) void*)l, 16, 0, 0);
}

// DPP quad_perm(1,0,3,2): swap adjacent lane pairs. VALU op, no LDS pipe.
__device__ __forceinline__ int dpp_swap1(int x) {
    return __builtin_amdgcn_update_dpp(0, x, 0xB1, 0xF, 0xF, true);
}

// ---------------------------------------------------------------------------
// fused f32 -> f16 cast over 4 tensors
// ---------------------------------------------------------------------------
__global__ __launch_bounds__(256) void cast4_f16(
    const float4* __restrict__ s0, ushort4* __restrict__ d0, int n0,
    const float4* __restrict__ s1, ushort4* __restrict__ d1, int n1,
    const float4* __restrict__ s2, ushort4* __restrict__ d2, int n2,
    const float4* __restrict__ s3, ushort4* __restrict__ d3, int n3)
{
    int i = blockIdx.x * 256 + threadIdx.x;
    const float4* s; ushort4* d; int idx;
    if (i < n0)                { s = s0; d = d0; idx = i; }
    else if (i < n0 + n1)      { s = s1; d = d1; idx = i - n0; }
    else if (i < n0 + n1 + n2) { s = s2; d = d2; idx = i - n0 - n1; }
    else if (i < n0 + n1 + n2 + n3) { s = s3; d = d3; idx = i - n0 - n1 - n2; }
    else return;
    float4 v = s[idx];
    _Float16 a = (_Float16)v.x, b = (_Float16)v.y,
             c = (_Float16)v.z, e = (_Float16)v.w;
    ushort4 o;
    o.x = *(unsigned short*)&a; o.y = *(unsigned short*)&b;
    o.z = *(unsigned short*)&c; o.w = *(unsigned short*)&e;
    d[idx] = o;
}

__global__ __launch_bounds__(256) void cast_f16(
    const float4* __restrict__ x, ushort4* __restrict__ y, int n4)
{
    int i = blockIdx.x * 256 + threadIdx.x;
    if (i >= n4) return;
    float4 v = x[i];
    _Float16 a = (_Float16)v.x, b = (_Float16)v.y,
             c = (_Float16)v.z, e = (_Float16)v.w;
    ushort4 o;
    o.x = *(unsigned short*)&a; o.y = *(unsigned short*)&b;
    o.z = *(unsigned short*)&c; o.w = *(unsigned short*)&e;
    y[i] = o;
}

// ---------------------------------------------------------------------------
// Fused QKV GEMM (m97-style staging). Grid (24, 16), 256 thr = 4 waves.
// bt<16: Q tile -> f16 scatter (b,h,s,d); 16..19: K -> f16; 20..23: V -> f16
// ---------------------------------------------------------------------------
__global__ __launch_bounds__(256) void qkv_gemm(
    const _Float16* __restrict__ A,
    const _Float16* __restrict__ Wq,
    const _Float16* __restrict__ Wk,
    const _Float16* __restrict__ Wv,
    _Float16* __restrict__ Cq, _Float16* __restrict__ Ck,
    _Float16* __restrict__ Cv)
{
    __shared__ __align__(16) _Float16 As[128][32];
    __shared__ __align__(16) _Float16 Ws[128][32];

    const int tid  = threadIdx.x;
    const int lane = tid & 63, wave = tid >> 6;
    const int wr = (wave >> 1) * 64, wc = (wave & 1) * 64;
    const int bm = blockIdx.y * 128;
    const int bt = blockIdx.x;

    const _Float16* Wsel;
    _Float16* Csel;
    int nrow0, heads;
    if (bt < 16)      { Wsel = Wq; Csel = Cq; nrow0 = bt * 128;        heads = NH_;  }
    else if (bt < 20) { Wsel = Wk; Csel = Ck; nrow0 = (bt - 16) * 128; heads = NKV_; }
    else              { Wsel = Wv; Csel = Cv; nrow0 = (bt - 20) * 128; heads = NKV_; }

    const int srow = 32 * wave + (lane >> 2);
    const int scol = (lane & 3) * 8;
    const _Float16* Ag = A    + (size_t)(bm + srow)    * HID_ + scol;
    const _Float16* Wg = Wsel + (size_t)(nrow0 + srow) * HID_ + scol;
    _Float16* lA = &As[32 * wave][0];
    _Float16* lW = &Ws[32 * wave][0];

    f32x4 acc[4][4];
    const f32x4 fz = {0.f, 0.f, 0.f, 0.f};
#pragma unroll
    for (int i = 0; i < 4; i++)
#pragma unroll
        for (int j = 0; j < 4; j++) acc[i][j] = fz;

    const int ml = lane & 15, kg = lane >> 4;

    for (int k0 = 0; k0 < HID_; k0 += 32) {
        __syncthreads();
        async_copy16(Ag + k0, lA);
        async_copy16(Ag + k0 + (size_t)16 * HID_, lA + 16 * 32);
        async_copy16(Wg + k0, lW);
        async_copy16(Wg + k0 + (size_t)16 * HID_, lW + 16 * 32);
        __syncthreads();

        f16x8 a[4], b[4];
#pragma unroll
        for (int mi = 0; mi < 4; mi++)
            a[mi] = *(const f16x8*)&As[wr + mi * 16 + ml][kg * 8];
#pragma unroll
        for (int ni = 0; ni < 4; ni++)
            b[ni] = *(const f16x8*)&Ws[wc + ni * 16 + ml][kg * 8];
#pragma unroll
        for (int mi = 0; mi < 4; mi++)
#pragma unroll
            for (int ni = 0; ni < 4; ni++)
                acc[mi][ni] = __builtin_amdgcn_mfma_f32_16x16x32_f16(
                    a[mi], b[ni], acc[mi][ni], 0, 0, 0);
    }

#pragma unroll
    for (int mi = 0; mi < 4; mi++) {
#pragma unroll
        for (int ni = 0; ni < 4; ni++) {
#pragma unroll
            for (int r = 0; r < 4; r++) {
                int m = bm + wr + mi * 16 + kg * 4 + r;
                int n = nrow0 + wc + ni * 16 + ml;
                int hh = n >> 7, d = n & 127;
                int b_ = m >> 10, s = m & 1023;
                size_t idx = (((size_t)(b_ * heads + hh)) * S_ + s) * HD_ + d;
                Csel[idx] = (_Float16)acc[mi][ni][r];
            }
        }
    }
}

// ---------------------------------------------------------------------------
// Output GEMM: C[m*2048+n] f32 = AO(2048x2048 f16) * Wo^T. Grid (16,16).
// ---------------------------------------------------------------------------
__global__ __launch_bounds__(256) void out_gemm(
    const _Float16* __restrict__ A,
    const _Float16* __restrict__ W,
    float* __restrict__ C)
{
    __shared__ __align__(16) _Float16 As[128][32];
    __shared__ __align__(16) _Float16 Ws[128][32];

    const int tid  = threadIdx.x;
    const int lane = tid & 63, wave = tid >> 6;
    const int wr = (wave >> 1) * 64, wc = (wave & 1) * 64;
    const int bm = blockIdx.y * 128, bn = blockIdx.x * 128;

    const int srow = 32 * wave + (lane >> 2);
    const int scol = (lane & 3) * 8;
    const _Float16* Ag = A + (size_t)(bm + srow) * HID_ + scol;
    const _Float16* Wg = W + (size_t)(bn + srow) * HID_ + scol;
    _Float16* lA = &As[32 * wave][0];
    _Float16* lW = &Ws[32 * wave][0];

    f32x4 acc[4][4];
    const f32x4 fz = {0.f, 0.f, 0.f, 0.f};
#pragma unroll
    for (int i = 0; i < 4; i++)
#pragma unroll
        for (int j = 0; j < 4; j++) acc[i][j] = fz;

    const int ml = lane & 15, kg = lane >> 4;

    for (int k0 = 0; k0 < HID_; k0 += 32) {
        __syncthreads();
        async_copy16(Ag + k0, lA);
        async_copy16(Ag + k0 + (size_t)16 * HID_, lA + 16 * 32);
        async_copy16(Wg + k0, lW);
        async_copy16(Wg + k0 + (size_t)16 * HID_, lW + 16 * 32);
        __syncthreads();

        f16x8 a[4], b[4];
#pragma unroll
        for (int mi = 0; mi < 4; mi++)
            a[mi] = *(const f16x8*)&As[wr + mi * 16 + ml][kg * 8];
#pragma unroll
        for (int ni = 0; ni < 4; ni++)
            b[ni] = *(const f16x8*)&Ws[wc + ni * 16 + ml][kg * 8];
#pragma unroll
        for (int mi = 0; mi < 4; mi++)
#pragma unroll
            for (int ni = 0; ni < 4; ni++)
                acc[mi][ni] = __builtin_amdgcn_mfma_f32_16x16x32_f16(
                    a[mi], b[ni], acc[mi][ni], 0, 0, 0);
    }

#pragma unroll
    for (int mi = 0; mi < 4; mi++)
#pragma unroll
        for (int ni = 0; ni < 4; ni++)
#pragma unroll
            for (int r = 0; r < 4; r++) {
                int m = bm + wr + mi * 16 + kg * 4 + r;
                int n = bn + wc + ni * 16 + ml;
                C[(size_t)m * HID_ + n] = acc[mi][ni][r];
            }
}

// ---------------------------------------------------------------------------
// Fused RoPE + RMSNorm over Q and K (f16 in, f16 out). Rows: 32768 Q + 8192 K.
// ---------------------------------------------------------------------------
__global__ __launch_bounds__(256) void rope_rms_f16(
    const _Float16* __restrict__ Qin, const _Float16* __restrict__ Kin,
    const float* __restrict__ qw, const float* __restrict__ kw,
    _Float16* __restrict__ Qout, _Float16* __restrict__ Kout)
{
    int row = blockIdx.x * 4 + (threadIdx.x >> 6);
    int lane = threadIdx.x & 63;
    bool isQ = row < 32768;
    int lrow = isQ ? row : row - 32768;
    const _Float16* p = (isQ ? Qin : Kin) + (size_t)lrow * HD_;
    _Float16* q = (isQ ? Qout : Kout) + (size_t)lrow * HD_;
    const float* w = isQ ? qw : kw;
    int s = row & (S_ - 1);

    float x1 = (float)p[lane], x2 = (float)p[lane + 64];

    float invf = exp2f(-(float)lane * 0.2076205059304601f);
    float ang = (float)s * invf;
    float c, sn;
    sincosf(ang, &sn, &c);

    float y1 = x1 * c - x2 * sn;
    float y2 = x1 * sn + x2 * c;

    float ss = y1 * y1 + y2 * y2;
#pragma unroll
    for (int off = 32; off > 0; off >>= 1) ss += __shfl_xor(ss, off);

    float scl = rsqrtf(ss * (1.0f / 128.0f) + 1e-6f);
    q[lane]      = (_Float16)(y1 * scl * w[lane]);
    q[lane + 64] = (_Float16)(y2 * scl * w[lane + 64]);
}

// ---------------------------------------------------------------------------
// MFMA stick-breaking attention. BQ=BK=64, 512 threads (8 waves).
// Flat grid 512: slot=bid&255 -> (b,h,i), phase=bid>>8 -> qb = phase? i : 15-i.
// Paired blocks (slot, slot+256) share a CU: 17 iters total + same K/V in L2.
// Sigmoid-domain: att = sig(L) * prod_{j<j'<i} sig(-L_j'); suffix products.
// ---------------------------------------------------------------------------
#define QK_STR 136
#define VT_STR 72
#define SS_STR 68
#define AT_STR 72

__global__ __launch_bounds__(512) void stick_attn(
    const _Float16* __restrict__ Q, const _Float16* __restrict__ K,
    const _Float16* __restrict__ V, _Float16* __restrict__ AO)
{
    __shared__ __align__(16) _Float16 Qs[64][QK_STR];
    __shared__ __align__(16) _Float16 Ks[64][QK_STR];
    __shared__ __align__(16) _Float16 Vt[128][VT_STR];
    __shared__ __align__(16) float    Ss[64][SS_STR];
    __shared__ __align__(16) _Float16 atts[64][AT_STR];
    __shared__ float paccs[64];

    const int bid = blockIdx.x;
    const int slot = bid & 255, phase = bid >> 8;
    const int hb = slot >> 3, iw = slot & 7;
    const int b = hb >> 4, h = hb & 15;
    const int qb = phase ? iw : 15 - iw;

    const int kvh = h / GROUPS;
    const int tid = threadIdx.x;
    const int lane = tid & 63, wave = tid >> 6;
    const int qw = wave >> 1;
    const int kh = wave & 1;
    const int ml = lane & 15, quad = lane >> 4;

    const _Float16* Kbase = K + ((size_t)(b * NKV_ + kvh) * S_) * HD_;
    const _Float16* Vbase = V + ((size_t)(b * NKV_ + kvh) * S_) * HD_;

    const f32x4 fz = {0.f, 0.f, 0.f, 0.f};

    const int qi0 = qb * 64;
    const _Float16* Qbase = Q + ((size_t)(b * NH_ + h) * S_ + qi0) * HD_;

    for (int idx = tid; idx < 64 * 16; idx += 512) {
        int r = idx >> 4, c8 = (idx & 15) * 8;
        *(f16x8*)&Qs[r][c8] = *(const f16x8*)(Qbase + r * HD_ + c8);
    }
    if (tid < 64) paccs[tid] = 1.f;
    __syncthreads();

    f16x8 aq[4];
#pragma unroll
    for (int ks = 0; ks < 4; ks++)
        aq[ks] = *(const f16x8*)&Qs[qw * 16 + ml][ks * 32 + quad * 8];

    f32x4 accO[4] = {fz, fz, fz, fz};

    for (int kb = qb; kb >= 0; --kb) {
        __syncthreads();

        // stage K (coalesced b128 writes)
        for (int idx = tid; idx < 64 * 16; idx += 512) {
            int r = idx >> 4, c8 = (idx & 15) * 8;
            *(f16x8*)&Ks[r][c8] =
                *(const f16x8*)(Kbase + (size_t)(kb * 64 + r) * HD_ + c8);
        }
        // stage V transposed: DPP pair-exchange + packed b32 writes (no conflicts)
        {
            int key = lane, dg = wave;
            const _Float16* vp =
                Vbase + (size_t)(kb * 64 + key) * HD_ + dg * 16;
            f16x8 v0 = *(const f16x8*)(vp);
            f16x8 v1 = *(const f16x8*)(vp + 8);
            int4 i0 = *(int4*)&v0, i1 = *(int4*)&v1;
            int4 p0, p1;
            p0.x = dpp_swap1(i0.x); p0.y = dpp_swap1(i0.y);
            p0.z = dpp_swap1(i0.z); p0.w = dpp_swap1(i0.w);
            p1.x = dpp_swap1(i1.x); p1.y = dpp_swap1(i1.y);
            p1.z = dpp_swap1(i1.z); p1.w = dpp_swap1(i1.w);
            bool ev = !(lane & 1);
            int4 al = ev ? i0 : p1;   // low halves: key 2k
            int4 bh = ev ? p0 : i1;   // high halves: key 2k+1
            int r0w = dg * 16 + (ev ? 0 : 8);
            int colk = lane & ~1;
            int ac[4] = {al.x, al.y, al.z, al.w};
            int bc[4] = {bh.x, bh.y, bh.z, bh.w};
#pragma unroll
            for (int i = 0; i < 8; i++) {
                int c = i >> 1;
                unsigned pack = (i & 1)
                    ? (((unsigned)ac[c] >> 16) | ((unsigned)bc[c] & 0xffff0000u))
                    : (((unsigned)ac[c] & 0xffffu) | ((unsigned)bc[c] << 16));
                *(unsigned*)&Vt[r0w + i][colk] = pack;
            }
        }
        __syncthreads();

        // QK^T -> Ss (scaled)
        f32x4 accS[2] = {fz, fz};
#pragma unroll
        for (int ks = 0; ks < 4; ks++) {
#pragma unroll
            for (int ni = 0; ni < 2; ni++) {
                f16x8 bf = *(const f16x8*)
                    &Ks[kh * 32 + ni * 16 + ml][ks * 32 + quad * 8];
                accS[ni] = __builtin_amdgcn_mfma_f32_16x16x32_f16(
                    aq[ks], bf, accS[ni], 0, 0, 0);
            }
        }
#pragma unroll
        for (int ni = 0; ni < 2; ni++)
#pragma unroll
            for (int r = 0; r < 4; r++)
                Ss[qw * 16 + quad * 4 + r][kh * 32 + ni * 16 + ml] =
                    accS[ni][r] * SCALE_;
        __syncthreads();

        // sigmoid-domain scan: om = sig(-L) exact, s = 1-om, suffix products
        {
            int q = tid >> 3, seg = tid & 7;
            int qg = qi0 + q;
            int j0 = kb * 64 + seg * 8;
            float4 s0 = *(float4*)&Ss[q][seg * 8];
            float4 s1 = *(float4*)&Ss[q][seg * 8 + 4];
            float L[8] = {s0.x, s0.y, s0.z, s0.w, s1.x, s1.y, s1.z, s1.w};
            float sv[8], om[8];
#pragma unroll
            for (int i = 0; i < 8; i++) {
                float u = __expf(L[i]);
                float o = __builtin_amdgcn_rcpf(1.f + u);   // sig(-L)
                bool valid = (j0 + i < qg);
                om[i] = valid ? o : 1.f;
                sv[i] = valid ? (1.f - o) : 0.f;            // sig(L)
            }
            float suf = 1.f, lo[8];
#pragma unroll
            for (int i = 7; i >= 0; --i) {
                lo[i] = suf; suf *= om[i];
            }
            float x = suf;
#pragma unroll
            for (int off = 1; off < 8; off <<= 1) {
                float y = __shfl_down(x, off);
                if (seg + off < 8) x *= y;
            }
            float bx = __shfl_down(x, 1);
            float base = (seg == 7) ? 1.f : bx;   // product of later segments
            float paccq = paccs[q];               // product of later k-blocks
            float pb = base * paccq;
            f16x8 av;
#pragma unroll
            for (int i = 0; i < 8; i++)
                av[i] = (_Float16)(sv[i] * lo[i] * pb);
            *(f16x8*)&atts[q][seg * 8] = av;
            if (seg == 0) paccs[q] = paccq * x;   // same-wave: reads precede
        }
        __syncthreads();

        // PV
#pragma unroll
        for (int ks = 0; ks < 2; ks++) {
            f16x8 ap = *(const f16x8*)&atts[qw * 16 + ml][ks * 32 + quad * 8];
#pragma unroll
            for (int ni = 0; ni < 4; ni++) {
                f16x8 bv = *(const f16x8*)
                    &Vt[kh * 64 + ni * 16 + ml][ks * 32 + quad * 8];
                accO[ni] = __builtin_amdgcn_mfma_f32_16x16x32_f16(
                    ap, bv, accO[ni], 0, 0, 0);
            }
        }
    }

#pragma unroll
    for (int ni = 0; ni < 4; ni++) {
#pragma unroll
        for (int r = 0; r < 4; r++) {
            int qg = qi0 + qw * 16 + quad * 4 + r;
            int d = kh * 64 + ni * 16 + ml;
            AO[((size_t)(b * S_ + qg) * NH_ + h) * HD_ + d] =
                (_Float16)accO[ni][r];
        }
    }
}

// ---------------------------------------------------------------------------
extern "C" void kernel_launch(void* const* d_in, const int* in_sizes, int n_in,
                              void* d_out, int out_size, void* d_ws, size_t ws_size,
                              hipStream_t stream)
{
    const float* hs = (const float*)d_in[0];
    const float* Wq = (const float*)d_in[1];
    const float* Wk = (const float*)d_in[2];
    const float* Wv = (const float*)d_in[3];
    const float* Wo = (const float*)d_in[4];
    const float* qw = (const float*)d_in[5];
    const float* kw = (const float*)d_in[6];
    float* out = (float*)d_out;

    // f16 workspace (reusing the old f32 region for Qg/Kg)
    _Float16* Qg  = (_Float16*)d_ws;            // 4,194,304 (pre-rope Q)
    _Float16* Kg  = Qg + 4194304;               // 1,048,576 (pre-rope K)
    _Float16* pad = Kg + 1048576;               // keep old layout alignment
    _Float16* hsh = (_Float16*)((float*)d_ws + 5242880);
    _Float16* Wqh = hsh + 4194304;
    _Float16* Wkh = Wqh + 4194304;
    _Float16* Wvh = Wkh + 1048576;
    _Float16* Qh  = Wvh + 1048576;              // 4,194,304 (post-rope Q)
    _Float16* Kh  = Qh + 4194304;               // 1,048,576 (post-rope K)
    _Float16* Vh  = Kh + 1048576;               // 1,048,576
    // stream-ordered aliases
    _Float16* AOh = hsh;   // after QKV gemm consumed hs
    _Float16* Woh = Wqh;   // after QKV gemm consumed Wq
    (void)pad;

    dim3 blk(256);

    // fused input casts: hs | Wq | Wk | Wv
    cast4_f16<<<10240, blk, 0, stream>>>(
        (const float4*)hs, (ushort4*)hsh, 1048576,
        (const float4*)Wq, (ushort4*)Wqh, 1048576,
        (const float4*)Wk, (ushort4*)Wkh, 262144,
        (const float4*)Wv, (ushort4*)Wvh, 262144);

    // fused QKV projection -> f16 (b,h,s,d)
    qkv_gemm<<<dim3(24, 16), blk, 0, stream>>>(hsh, Wqh, Wkh, Wvh,
                                               Qg, Kg, Vh);

    // Wo cast (reuses Wq's f16 buffer)
    cast_f16<<<4096, blk, 0, stream>>>((const float4*)Wo, (ushort4*)Woh, 1048576);

    // fused RoPE + RMSNorm for Q and K (f16 -> f16)
    rope_rms_f16<<<dim3((32768 + 8192) / 4), blk, 0, stream>>>(
        Qg, Kg, qw, kw, Qh, Kh);

    // stick-breaking attention -> f16 (b,s,h,d)
    stick_attn<<<dim3(512), dim3(512), 0, stream>>>(Qh, Kh, Vh, AOh);

    // output projection
    out_gemm<<<dim3(16, 16), blk, 0, stream>>>(AOh, Woh, out);
}

// Round 6
// 239.661 us; speedup vs baseline: 6.4481x; 1.0377x over previous
//
#include <hip/hip_runtime.h>
#include <math.h>

#define B_    2
#define S_    1024
#define HID_  2048
#define NH_   16
#define NKV_  4
#define HD_   128
#define GROUPS (NH_ / NKV_)
#define SCALE_ 0.08838834764831845f   // 1/sqrt(128)

typedef _Float16 f16x8 __attribute__((ext_vector_type(8)));
typedef float    f32x4 __attribute__((ext_vector_type(4)));

// async global->LDS, 16B per lane; LDS dest = wave-uniform base + lane*16
__device__ __forceinline__ void async_copy16(const void* g, void* l) {
    __builtin_amdgcn_global_load_lds(
        (const __attribute__((address_space(1))) void*)g,
        (__attribute__((address_space(3))) void*)l, 16, 0, 0);
}

// DPP quad_perm(1,0,3,2): swap adjacent lane pairs. VALU op, no LDS pipe.
__device__ __forceinline__ int dpp_swap1(int x) {
    return __builtin_amdgcn_update_dpp(0, x, 0xB1, 0xF, 0xF, true);
}

// ---------------------------------------------------------------------------
// fused f32 -> f16 cast over 5 tensors (one launch for all inputs)
// ---------------------------------------------------------------------------
__global__ __launch_bounds__(256) void cast5_f16(
    const float4* __restrict__ s0, ushort4* __restrict__ d0, int n0,
    const float4* __restrict__ s1, ushort4* __restrict__ d1, int n1,
    const float4* __restrict__ s2, ushort4* __restrict__ d2, int n2,
    const float4* __restrict__ s3, ushort4* __restrict__ d3, int n3,
    const float4* __restrict__ s4, ushort4* __restrict__ d4, int n4)
{
    int i = blockIdx.x * 256 + threadIdx.x;
    const float4* s; ushort4* d; int idx;
    if (i < n0)                          { s = s0; d = d0; idx = i; }
    else if (i < n0 + n1)                { s = s1; d = d1; idx = i - n0; }
    else if (i < n0 + n1 + n2)           { s = s2; d = d2; idx = i - n0 - n1; }
    else if (i < n0 + n1 + n2 + n3)      { s = s3; d = d3; idx = i - n0 - n1 - n2; }
    else if (i < n0 + n1 + n2 + n3 + n4) { s = s4; d = d4; idx = i - n0 - n1 - n2 - n3; }
    else return;
    float4 v = s[idx];
    _Float16 a = (_Float16)v.x, b = (_Float16)v.y,
             c = (_Float16)v.z, e = (_Float16)v.w;
    ushort4 o;
    o.x = *(unsigned short*)&a; o.y = *(unsigned short*)&b;
    o.z = *(unsigned short*)&c; o.w = *(unsigned short*)&e;
    d[idx] = o;
}

// ---------------------------------------------------------------------------
// Fused QKV GEMM, 128x64 (MxN) tiles, grid (48,16) = 768 blocks = 3/CU.
// bt<32: Q cols; 32..39: K cols; 40..47: V cols. All outputs f16 (b,h,s,d).
// 256 thr = 4 waves; wave w: rows (w>>1)*64, cols (w&1)*32 -> 4x2 frags.
// ---------------------------------------------------------------------------
__global__ __launch_bounds__(256) void qkv_gemm(
    const _Float16* __restrict__ A,
    const _Float16* __restrict__ Wq,
    const _Float16* __restrict__ Wk,
    const _Float16* __restrict__ Wv,
    _Float16* __restrict__ Cq, _Float16* __restrict__ Ck,
    _Float16* __restrict__ Cv)
{
    __shared__ __align__(16) _Float16 As[128][32];
    __shared__ __align__(16) _Float16 Ws[64][32];

    const int tid  = threadIdx.x;
    const int lane = tid & 63, wave = tid >> 6;
    const int bm = blockIdx.y * 128;
    const int bt = blockIdx.x;

    const _Float16* Wsel;
    _Float16* Csel;
    int n0, heads;
    if (bt < 32)      { Wsel = Wq; Csel = Cq; n0 = bt * 64;        heads = NH_;  }
    else if (bt < 40) { Wsel = Wk; Csel = Ck; n0 = (bt - 32) * 64; heads = NKV_; }
    else              { Wsel = Wv; Csel = Cv; n0 = (bt - 40) * 64; heads = NKV_; }

    const int rsub = lane >> 2;          // 0..15
    const int csub = (lane & 3) * 8;     // f16 col within 32
    const _Float16* Ag0 = A    + (size_t)(bm + wave * 16 + rsub) * HID_ + csub;
    const _Float16* Ag1 = Ag0  + (size_t)64 * HID_;
    const _Float16* Wg  = Wsel + (size_t)(n0 + wave * 16 + rsub) * HID_ + csub;
    _Float16* ldsA0 = &As[wave * 16][0];
    _Float16* ldsA1 = &As[64 + wave * 16][0];
    _Float16* ldsW  = &Ws[wave * 16][0];

    f32x4 acc[4][2];
    const f32x4 fz = {0.f, 0.f, 0.f, 0.f};
#pragma unroll
    for (int i = 0; i < 4; i++)
#pragma unroll
        for (int j = 0; j < 2; j++) acc[i][j] = fz;

    const int ml = lane & 15, kg = lane >> 4;
    const int mrow = (wave >> 1) * 64, ncol = (wave & 1) * 32;

    for (int k0 = 0; k0 < HID_; k0 += 32) {
        __syncthreads();
        async_copy16(Ag0 + k0, ldsA0);
        async_copy16(Ag1 + k0, ldsA1);
        async_copy16(Wg  + k0, ldsW);
        __syncthreads();

        f16x8 a[4], b[2];
#pragma unroll
        for (int mi = 0; mi < 4; mi++)
            a[mi] = *(const f16x8*)&As[mrow + mi * 16 + ml][kg * 8];
#pragma unroll
        for (int ni = 0; ni < 2; ni++)
            b[ni] = *(const f16x8*)&Ws[ncol + ni * 16 + ml][kg * 8];
#pragma unroll
        for (int mi = 0; mi < 4; mi++)
#pragma unroll
            for (int ni = 0; ni < 2; ni++)
                acc[mi][ni] = __builtin_amdgcn_mfma_f32_16x16x32_f16(
                    a[mi], b[ni], acc[mi][ni], 0, 0, 0);
    }

#pragma unroll
    for (int mi = 0; mi < 4; mi++) {
#pragma unroll
        for (int ni = 0; ni < 2; ni++) {
#pragma unroll
            for (int r = 0; r < 4; r++) {
                int m = bm + mrow + mi * 16 + kg * 4 + r;
                int n = n0 + ncol + ni * 16 + ml;
                int hh = n >> 7, d = n & 127;
                int b_ = m >> 10, s = m & 1023;
                size_t idx = (((size_t)(b_ * heads + hh)) * S_ + s) * HD_ + d;
                Csel[idx] = (_Float16)acc[mi][ni][r];
            }
        }
    }
}

// ---------------------------------------------------------------------------
// Output GEMM: 128x64 tiles, grid (32,16) = 512 blocks = 2/CU. f32 out.
// ---------------------------------------------------------------------------
__global__ __launch_bounds__(256) void out_gemm(
    const _Float16* __restrict__ A,
    const _Float16* __restrict__ W,
    float* __restrict__ C)
{
    __shared__ __align__(16) _Float16 As[128][32];
    __shared__ __align__(16) _Float16 Ws[64][32];

    const int tid  = threadIdx.x;
    const int lane = tid & 63, wave = tid >> 6;
    const int bm = blockIdx.y * 128;
    const int bn = blockIdx.x * 64;

    const int rsub = lane >> 2;
    const int csub = (lane & 3) * 8;
    const _Float16* Ag0 = A + (size_t)(bm + wave * 16 + rsub) * HID_ + csub;
    const _Float16* Ag1 = Ag0 + (size_t)64 * HID_;
    const _Float16* Wg  = W + (size_t)(bn + wave * 16 + rsub) * HID_ + csub;
    _Float16* ldsA0 = &As[wave * 16][0];
    _Float16* ldsA1 = &As[64 + wave * 16][0];
    _Float16* ldsW  = &Ws[wave * 16][0];

    f32x4 acc[4][2];
    const f32x4 fz = {0.f, 0.f, 0.f, 0.f};
#pragma unroll
    for (int i = 0; i < 4; i++)
#pragma unroll
        for (int j = 0; j < 2; j++) acc[i][j] = fz;

    const int ml = lane & 15, kg = lane >> 4;
    const int mrow = (wave >> 1) * 64, ncol = (wave & 1) * 32;

    for (int k0 = 0; k0 < HID_; k0 += 32) {
        __syncthreads();
        async_copy16(Ag0 + k0, ldsA0);
        async_copy16(Ag1 + k0, ldsA1);
        async_copy16(Wg  + k0, ldsW);
        __syncthreads();

        f16x8 a[4], b[2];
#pragma unroll
        for (int mi = 0; mi < 4; mi++)
            a[mi] = *(const f16x8*)&As[mrow + mi * 16 + ml][kg * 8];
#pragma unroll
        for (int ni = 0; ni < 2; ni++)
            b[ni] = *(const f16x8*)&Ws[ncol + ni * 16 + ml][kg * 8];
#pragma unroll
        for (int mi = 0; mi < 4; mi++)
#pragma unroll
            for (int ni = 0; ni < 2; ni++)
                acc[mi][ni] = __builtin_amdgcn_mfma_f32_16x16x32_f16(
                    a[mi], b[ni], acc[mi][ni], 0, 0, 0);
    }

#pragma unroll
    for (int mi = 0; mi < 4; mi++)
#pragma unroll
        for (int ni = 0; ni < 2; ni++)
#pragma unroll
            for (int r = 0; r < 4; r++) {
                int m = bm + mrow + mi * 16 + kg * 4 + r;
                int n = bn + ncol + ni * 16 + ml;
                C[(size_t)m * HID_ + n] = acc[mi][ni][r];
            }
}

// ---------------------------------------------------------------------------
// Fused RoPE + RMSNorm over Q and K (f16 in, f16 out). Rows: 32768 Q + 8192 K.
// ---------------------------------------------------------------------------
__global__ __launch_bounds__(256) void rope_rms_f16(
    const _Float16* __restrict__ Qin, const _Float16* __restrict__ Kin,
    const float* __restrict__ qw, const float* __restrict__ kw,
    _Float16* __restrict__ Qout, _Float16* __restrict__ Kout)
{
    int row = blockIdx.x * 4 + (threadIdx.x >> 6);
    int lane = threadIdx.x & 63;
    bool isQ = row < 32768;
    int lrow = isQ ? row : row - 32768;
    const _Float16* p = (isQ ? Qin : Kin) + (size_t)lrow * HD_;
    _Float16* q = (isQ ? Qout : Kout) + (size_t)lrow * HD_;
    const float* w = isQ ? qw : kw;
    int s = row & (S_ - 1);

    float x1 = (float)p[lane], x2 = (float)p[lane + 64];

    float invf = exp2f(-(float)lane * 0.2076205059304601f);
    float ang = (float)s * invf;
    float c, sn;
    sincosf(ang, &sn, &c);

    float y1 = x1 * c - x2 * sn;
    float y2 = x1 * sn + x2 * c;

    float ss = y1 * y1 + y2 * y2;
#pragma unroll
    for (int off = 32; off > 0; off >>= 1) ss += __shfl_xor(ss, off);

    float scl = rsqrtf(ss * (1.0f / 128.0f) + 1e-6f);
    q[lane]      = (_Float16)(y1 * scl * w[lane]);
    q[lane + 64] = (_Float16)(y2 * scl * w[lane + 64]);
}

// ---------------------------------------------------------------------------
// MFMA stick-breaking attention (unchanged from round 5).
// ---------------------------------------------------------------------------
#define QK_STR 136
#define VT_STR 72
#define SS_STR 68
#define AT_STR 72

__global__ __launch_bounds__(512) void stick_attn(
    const _Float16* __restrict__ Q, const _Float16* __restrict__ K,
    const _Float16* __restrict__ V, _Float16* __restrict__ AO)
{
    __shared__ __align__(16) _Float16 Qs[64][QK_STR];
    __shared__ __align__(16) _Float16 Ks[64][QK_STR];
    __shared__ __align__(16) _Float16 Vt[128][VT_STR];
    __shared__ __align__(16) float    Ss[64][SS_STR];
    __shared__ __align__(16) _Float16 atts[64][AT_STR];
    __shared__ float paccs[64];

    const int bid = blockIdx.x;
    const int slot = bid & 255, phase = bid >> 8;
    const int hb = slot >> 3, iw = slot & 7;
    const int b = hb >> 4, h = hb & 15;
    const int qb = phase ? iw : 15 - iw;

    const int kvh = h / GROUPS;
    const int tid = threadIdx.x;
    const int lane = tid & 63, wave = tid >> 6;
    const int qw = wave >> 1;
    const int kh = wave & 1;
    const int ml = lane & 15, quad = lane >> 4;

    const _Float16* Kbase = K + ((size_t)(b * NKV_ + kvh) * S_) * HD_;
    const _Float16* Vbase = V + ((size_t)(b * NKV_ + kvh) * S_) * HD_;

    const f32x4 fz = {0.f, 0.f, 0.f, 0.f};

    const int qi0 = qb * 64;
    const _Float16* Qbase = Q + ((size_t)(b * NH_ + h) * S_ + qi0) * HD_;

    for (int idx = tid; idx < 64 * 16; idx += 512) {
        int r = idx >> 4, c8 = (idx & 15) * 8;
        *(f16x8*)&Qs[r][c8] = *(const f16x8*)(Qbase + r * HD_ + c8);
    }
    if (tid < 64) paccs[tid] = 1.f;
    __syncthreads();

    f16x8 aq[4];
#pragma unroll
    for (int ks = 0; ks < 4; ks++)
        aq[ks] = *(const f16x8*)&Qs[qw * 16 + ml][ks * 32 + quad * 8];

    f32x4 accO[4] = {fz, fz, fz, fz};

    for (int kb = qb; kb >= 0; --kb) {
        __syncthreads();

        for (int idx = tid; idx < 64 * 16; idx += 512) {
            int r = idx >> 4, c8 = (idx & 15) * 8;
            *(f16x8*)&Ks[r][c8] =
                *(const f16x8*)(Kbase + (size_t)(kb * 64 + r) * HD_ + c8);
        }
        {
            int key = lane, dg = wave;
            const _Float16* vp =
                Vbase + (size_t)(kb * 64 + key) * HD_ + dg * 16;
            f16x8 v0 = *(const f16x8*)(vp);
            f16x8 v1 = *(const f16x8*)(vp + 8);
            int4 i0 = *(int4*)&v0, i1 = *(int4*)&v1;
            int4 p0, p1;
            p0.x = dpp_swap1(i0.x); p0.y = dpp_swap1(i0.y);
            p0.z = dpp_swap1(i0.z); p0.w = dpp_swap1(i0.w);
            p1.x = dpp_swap1(i1.x); p1.y = dpp_swap1(i1.y);
            p1.z = dpp_swap1(i1.z); p1.w = dpp_swap1(i1.w);
            bool ev = !(lane & 1);
            int4 al = ev ? i0 : p1;
            int4 bh = ev ? p0 : i1;
            int r0w = dg * 16 + (ev ? 0 : 8);
            int colk = lane & ~1;
            int ac[4] = {al.x, al.y, al.z, al.w};
            int bc[4] = {bh.x, bh.y, bh.z, bh.w};
#pragma unroll
            for (int i = 0; i < 8; i++) {
                int c = i >> 1;
                unsigned pack = (i & 1)
                    ? (((unsigned)ac[c] >> 16) | ((unsigned)bc[c] & 0xffff0000u))
                    : (((unsigned)ac[c] & 0xffffu) | ((unsigned)bc[c] << 16));
                *(unsigned*)&Vt[r0w + i][colk] = pack;
            }
        }
        __syncthreads();

        f32x4 accS[2] = {fz, fz};
#pragma unroll
        for (int ks = 0; ks < 4; ks++) {
#pragma unroll
            for (int ni = 0; ni < 2; ni++) {
                f16x8 bf = *(const f16x8*)
                    &Ks[kh * 32 + ni * 16 + ml][ks * 32 + quad * 8];
                accS[ni] = __builtin_amdgcn_mfma_f32_16x16x32_f16(
                    aq[ks], bf, accS[ni], 0, 0, 0);
            }
        }
#pragma unroll
        for (int ni = 0; ni < 2; ni++)
#pragma unroll
            for (int r = 0; r < 4; r++)
                Ss[qw * 16 + quad * 4 + r][kh * 32 + ni * 16 + ml] =
                    accS[ni][r] * SCALE_;
        __syncthreads();

        {
            int q = tid >> 3, seg = tid & 7;
            int qg = qi0 + q;
            int j0 = kb * 64 + seg * 8;
            float4 s0 = *(float4*)&Ss[q][seg * 8];
            float4 s1 = *(float4*)&Ss[q][seg * 8 + 4];
            float L[8] = {s0.x, s0.y, s0.z, s0.w, s1.x, s1.y, s1.z, s1.w};
            float sv[8], om[8];
#pragma unroll
            for (int i = 0; i < 8; i++) {
                float u = __expf(L[i]);
                float o = __builtin_amdgcn_rcpf(1.f + u);
                bool valid = (j0 + i < qg);
                om[i] = valid ? o : 1.f;
                sv[i] = valid ? (1.f - o) : 0.f;
            }
            float suf = 1.f, lo[8];
#pragma unroll
            for (int i = 7; i >= 0; --i) {
                lo[i] = suf; suf *= om[i];
            }
            float x = suf;
#pragma unroll
            for (int off = 1; off < 8; off <<= 1) {
                float y = __shfl_down(x, off);
                if (seg + off < 8) x *= y;
            }
            float bx = __shfl_down(x, 1);
            float base = (seg == 7) ? 1.f : bx;
            float paccq = paccs[q];
            float pb = base * paccq;
            f16x8 av;
#pragma unroll
            for (int i = 0; i < 8; i++)
                av[i] = (_Float16)(sv[i] * lo[i] * pb);
            *(f16x8*)&atts[q][seg * 8] = av;
            if (seg == 0) paccs[q] = paccq * x;
        }
        __syncthreads();

#pragma unroll
        for (int ks = 0; ks < 2; ks++) {
            f16x8 ap = *(const f16x8*)&atts[qw * 16 + ml][ks * 32 + quad * 8];
#pragma unroll
            for (int ni = 0; ni < 4; ni++) {
                f16x8 bv = *(const f16x8*)
                    &Vt[kh * 64 + ni * 16 + ml][ks * 32 + quad * 8];
                accO[ni] = __builtin_amdgcn_mfma_f32_16x16x32_f16(
                    ap, bv, accO[ni], 0, 0, 0);
            }
        }
    }

#pragma unroll
    for (int ni = 0; ni < 4; ni++) {
#pragma unroll
        for (int r = 0; r < 4; r++) {
            int qg = qi0 + qw * 16 + quad * 4 + r;
            int d = kh * 64 + ni * 16 + ml;
            AO[((size_t)(b * S_ + qg) * NH_ + h) * HD_ + d] =
                (_Float16)accO[ni][r];
        }
    }
}

// ---------------------------------------------------------------------------
extern "C" void kernel_launch(void* const* d_in, const int* in_sizes, int n_in,
                              void* d_out, int out_size, void* d_ws, size_t ws_size,
                              hipStream_t stream)
{
    const float* hs = (const float*)d_in[0];
    const float* Wq = (const float*)d_in[1];
    const float* Wk = (const float*)d_in[2];
    const float* Wv = (const float*)d_in[3];
    const float* Wo = (const float*)d_in[4];
    const float* qw = (const float*)d_in[5];
    const float* kw = (const float*)d_in[6];
    float* out = (float*)d_out;

    // region 1 (20 MB): pre-rope Q/K + Wo f16
    _Float16* Qg  = (_Float16*)d_ws;            // 4,194,304 f16
    _Float16* Kg  = Qg + 4194304;               // 1,048,576 f16
    _Float16* Woh = Kg + 1048576;               // 4,194,304 f16 (fits: 18 MB < 20 MB)
    // region 2: f16 inputs + post-rope tensors
    _Float16* hsh = (_Float16*)((float*)d_ws + 5242880);
    _Float16* Wqh = hsh + 4194304;
    _Float16* Wkh = Wqh + 4194304;
    _Float16* Wvh = Wkh + 1048576;
    _Float16* Qh  = Wvh + 1048576;              // post-rope Q
    _Float16* Kh  = Qh + 4194304;               // post-rope K
    _Float16* Vh  = Kh + 1048576;               // V
    // stream-ordered alias
    _Float16* AOh = hsh;   // attention out, after qkv consumed hs

    dim3 blk(256);

    // one launch: cast hs | Wq | Wk | Wv | Wo to f16
    cast5_f16<<<14336, blk, 0, stream>>>(
        (const float4*)hs, (ushort4*)hsh, 1048576,
        (const float4*)Wq, (ushort4*)Wqh, 1048576,
        (const float4*)Wk, (ushort4*)Wkh, 262144,
        (const float4*)Wv, (ushort4*)Wvh, 262144,
        (const float4*)Wo, (ushort4*)Woh, 1048576);

    // fused QKV projection -> f16 (b,h,s,d); 768 blocks = 3/CU
    qkv_gemm<<<dim3(48, 16), blk, 0, stream>>>(hsh, Wqh, Wkh, Wvh,
                                               Qg, Kg, Vh);

    // fused RoPE + RMSNorm for Q and K
    rope_rms_f16<<<dim3((32768 + 8192) / 4), blk, 0, stream>>>(
        Qg, Kg, qw, kw, Qh, Kh);

    // stick-breaking attention -> f16 (b,s,h,d)
    stick_attn<<<dim3(512), dim3(512), 0, stream>>>(Qh, Kh, Vh, AOh);

    // output projection; 512 blocks = 2/CU
    out_gemm<<<dim3(32, 16), blk, 0, stream>>>(AOh, Woh, out);
}